// Round 3
// baseline (4095.867 us; speedup 1.0000x reference)
//
#include <hip/hip_runtime.h>
#include <hip/hip_bf16.h>

typedef __hip_bfloat16 bf16;

// Problem constants: x (L=1024, N=8, C=1024), H=16 heads, hd=64
#define LOGIT_MAX 4.6051702f   // log(1/0.01)

// exact bf16 -> fp32 from packed uint halves (little-endian: lo = even elem)
__device__ __forceinline__ float bflo(unsigned u) {
    union { unsigned x; float f; } c; c.x = u << 16; return c.f;
}
__device__ __forceinline__ float bfhi(unsigned u) {
    union { unsigned x; float f; } c; c.x = u & 0xffff0000u; return c.f;
}

// scalar load -> fp32, overloaded on source type
__device__ __forceinline__ float ldf(const float* p) { return *p; }
__device__ __forceinline__ float ldf(const bf16*  p) { return __bfloat162float(*p); }

// 4-contiguous-element load -> float4 (addr must be 4-elem aligned)
__device__ __forceinline__ float4 load4(const float* p) { return *(const float4*)p; }
__device__ __forceinline__ float4 load4(const bf16* p) {
    const uint2 u = *(const uint2*)p;
    return make_float4(bflo(u.x), bfhi(u.x), bflo(u.y), bfhi(u.y));
}

// store fp32 value as output element type
__device__ __forceinline__ void stf(float* p, float v) { *p = v; }
__device__ __forceinline__ void stf(bf16*  p, float v) { *p = __float2bfloat16(v); }

// ---------------------------------------------------------------------------
// Kernel 0: dtype detection. bf16 N(0,1)-scale data has exponent field
// < 0x90 (|v| < 2^17) essentially always; fp32 data read as uint16 has
// uniform-random low halves -> ~44% of even elements "wild". flag: 1 = fp32.
// ---------------------------------------------------------------------------
__global__ void detect_kernel(const unsigned short* __restrict__ x, int* __restrict__ flag)
{
    __shared__ int cnt;
    if (threadIdx.x == 0) cnt = 0;
    __syncthreads();
    int c = 0;
    for (int i = threadIdx.x; i < 4096; i += 256) {
        const unsigned e = (x[i] >> 7) & 0xFF;
        if (e >= 0x90) c++;
    }
    atomicAdd(&cnt, c);
    __syncthreads();
    if (threadIdx.x == 0) *flag = (cnt > 64) ? 1 : 0;
}

// ---------------------------------------------------------------------------
// Kernel 0b: convert small vectors to fp32 ws buffer (gated by mode):
// dst[0:3072)   = in_proj_bias
// dst[3072:4096)= out_b
// dst[4096:4112)= exp(min(logit_scale, LOGIT_MAX))
// dst[4112:4128)= head_scale
// ---------------------------------------------------------------------------
template <typename T>
__global__ void convert_small_kernel(const int* __restrict__ flag, int mode,
                                     const T* __restrict__ b_in, const T* __restrict__ out_b,
                                     const T* __restrict__ ls, const T* __restrict__ hs,
                                     float* __restrict__ dst)
{
    if (*flag != mode) return;
    for (int idx = threadIdx.x; idx < 4128; idx += 256) {
        float v;
        if (idx < 3072)      v = ldf(b_in + idx);
        else if (idx < 4096) v = ldf(out_b + (idx - 3072));
        else if (idx < 4112) v = expf(fminf(ldf(ls + (idx - 4096)), LOGIT_MAX));
        else                 v = ldf(hs + (idx - 4112));
        dst[idx] = v;
    }
}

// ---------------------------------------------------------------------------
// Kernel 1: QKV projection.  out[r][c] = sum_k X[r][k]*W[c][k] + bias[c]
// M=8192 (r = l*8+n), K=1024, Ncols=3072. Scatter into q/k/v (N,H,L,hd) bf16.
// 64x64 tile, BK=16, 256 threads, 4x4 micro-tile, fp32 accumulate.
// ---------------------------------------------------------------------------
template <typename T>
__global__ __launch_bounds__(256) void qkv_gemm_kernel(
    const int* __restrict__ flag, int mode,
    const T* __restrict__ X, const T* __restrict__ W,
    const float* __restrict__ bias_f,
    bf16* __restrict__ q, bf16* __restrict__ k, bf16* __restrict__ v)
{
    if (*flag != mode) return;
    __shared__ float As[16][68];   // [k][m]
    __shared__ float Bs[16][68];   // [k][n]
    const int tid  = threadIdx.x;
    const int tx   = tid & 15, ty = tid >> 4;
    const int row0 = blockIdx.y * 64;
    const int col0 = blockIdx.x * 64;
    const int lrow = tid >> 2;          // 0..63
    const int lk   = (tid & 3) * 4;     // 0,4,8,12
    float acc[4][4] = {};

    for (int kt = 0; kt < 1024; kt += 16) {
        const float4 a = load4(X + (size_t)(row0 + lrow) * 1024 + kt + lk);
        const float4 b = load4(W + (size_t)(col0 + lrow) * 1024 + kt + lk);
        As[lk + 0][lrow] = a.x; As[lk + 1][lrow] = a.y;
        As[lk + 2][lrow] = a.z; As[lk + 3][lrow] = a.w;
        Bs[lk + 0][lrow] = b.x; Bs[lk + 1][lrow] = b.y;
        Bs[lk + 2][lrow] = b.z; Bs[lk + 3][lrow] = b.w;
        __syncthreads();
#pragma unroll
        for (int kk = 0; kk < 16; kk++) {
            const float4 aa = *(const float4*)&As[kk][ty * 4];
            const float4 bb = *(const float4*)&Bs[kk][tx * 4];
            const float avv[4] = {aa.x, aa.y, aa.z, aa.w};
            const float bvv[4] = {bb.x, bb.y, bb.z, bb.w};
#pragma unroll
            for (int i = 0; i < 4; i++)
#pragma unroll
                for (int j = 0; j < 4; j++) acc[i][j] += avv[i] * bvv[j];
        }
        __syncthreads();
    }

    // Scatter with bias: c -> (part, h, d); r -> (l, n); dst[(n*16+h)*1024+l][d]
#pragma unroll
    for (int i = 0; i < 4; i++) {
        const int r = row0 + ty * 4 + i;
        const int l = r >> 3, n = r & 7;
#pragma unroll
        for (int j = 0; j < 4; j++) {
            const int c   = col0 + tx * 4 + j;
            const float val = acc[i][j] + bias_f[c];
            const int part = c >> 10;
            const int cc   = c & 1023;
            const int h = cc >> 6, d = cc & 63;
            bf16* dst = (part == 0) ? q : ((part == 1) ? k : v);
            dst[((size_t)((n * 16 + h) * 1024 + l)) * 64 + d] = __float2bfloat16(val);
        }
    }
}

// ---------------------------------------------------------------------------
// Kernel 2: L2-normalize rows of 64 (q then k contiguous: 2*8*16*1024 rows).
// One wave per row, fp32 math, bf16 in/out. Matches F.normalize semantics.
// ---------------------------------------------------------------------------
__global__ __launch_bounds__(256) void normalize_kernel(bf16* __restrict__ qk)
{
    const int row  = blockIdx.x * 4 + (threadIdx.x >> 6);
    const int lane = threadIdx.x & 63;
    bf16* p = qk + (size_t)row * 64;
    const float val = __bfloat162float(p[lane]);
    float ss = val * val;
#pragma unroll
    for (int off = 32; off > 0; off >>= 1) ss += __shfl_down(ss, off, 64);
    ss = __shfl(ss, 0, 64);
    const float dn = fmaxf(sqrtf(ss), 1e-12f);
    p[lane] = __float2bfloat16(val / dn);
}

// ---------------------------------------------------------------------------
// Kernel 3: attention. One wave per query row (4 rows/block), fp32 math.
// scale_f: [4096..4112) = exp(min(ls,max)) per head, [4112..4128) head_scale.
// ---------------------------------------------------------------------------
__global__ __launch_bounds__(256) void attn_kernel(
    const bf16* __restrict__ q, const bf16* __restrict__ k,
    const bf16* __restrict__ v, const float* __restrict__ scale_f,
    bf16* __restrict__ o)
{
    __shared__ float s_lds[4][1024];
    __shared__ float qs[4][64];
    const int bid  = blockIdx.x;            // ((n*16+h)*256 + l4)
    const int l4   = bid & 255;
    const int h    = (bid >> 8) & 15;
    const int n    = bid >> 12;
    const int w    = threadIdx.x >> 6;      // wave id 0..3
    const int lane = threadIdx.x & 63;
    const int l    = l4 * 4 + w;
    const size_t base = (size_t)(n * 16 + h) * (1024 * 64);

    qs[w][lane] = __bfloat162float(q[base + (size_t)l * 64 + lane]);
    __syncthreads();

    const float ls = scale_f[4096 + h];
    const float hs = scale_f[4112 + h];

    // scores for this wave's query row; k row = 64 bf16 = 128 B = 8 x uint4
    float lmax = -1e30f;
    for (int m = lane; m < 1024; m += 64) {
        const uint4* kp4 = (const uint4*)(k + base + (size_t)m * 64);
        float s = 0.f;
#pragma unroll
        for (int i = 0; i < 8; i++) {
            const uint4 kv = kp4[i];
            const float* qp = &qs[w][i * 8];
            s += qp[0] * bflo(kv.x) + qp[1] * bfhi(kv.x)
               + qp[2] * bflo(kv.y) + qp[3] * bfhi(kv.y)
               + qp[4] * bflo(kv.z) + qp[5] * bfhi(kv.z)
               + qp[6] * bflo(kv.w) + qp[7] * bfhi(kv.w);
        }
        s *= ls;
        s_lds[w][m] = s;
        lmax = fmaxf(lmax, s);
    }
#pragma unroll
    for (int off = 32; off > 0; off >>= 1) lmax = fmaxf(lmax, __shfl_down(lmax, off, 64));
    lmax = __shfl(lmax, 0, 64);

    float lsum = 0.f;
    for (int m = lane; m < 1024; m += 64) {
        const float p = expf(s_lds[w][m] - lmax);
        s_lds[w][m] = p;
        lsum += p;
    }
#pragma unroll
    for (int off = 32; off > 0; off >>= 1) lsum += __shfl_down(lsum, off, 64);
    lsum = __shfl(lsum, 0, 64);
    const float scale = hs / lsum;

    // o accumulation: lane == d, coalesced V reads
    float acc = 0.f;
    const bf16* vp = v + base + lane;
#pragma unroll 4
    for (int m = 0; m < 1024; m++) acc += s_lds[w][m] * __bfloat162float(vp[(size_t)m * 64]);

    // o layout (L*N, C): row l*8+n, col h*64+d
    o[((size_t)(l * 8 + n)) * 1024 + h * 64 + lane] = __float2bfloat16(acc * scale);
}

// ---------------------------------------------------------------------------
// Kernel 4: out projection. out[r][c] = sum_k A[r][k]*W[c][k] + b[c].
// M=8192, N=1024, K=1024. A is bf16 ws; W and out follow detected dtype.
// ---------------------------------------------------------------------------
template <typename T>
__global__ __launch_bounds__(256) void out_gemm_kernel(
    const int* __restrict__ flag, int mode,
    const bf16* __restrict__ A, const T* __restrict__ W,
    const float* __restrict__ bias_f, T* __restrict__ out)
{
    if (*flag != mode) return;
    __shared__ float As[16][68];
    __shared__ float Bs[16][68];
    const int tid  = threadIdx.x;
    const int tx   = tid & 15, ty = tid >> 4;
    const int row0 = blockIdx.y * 64;
    const int col0 = blockIdx.x * 64;
    const int lrow = tid >> 2;
    const int lk   = (tid & 3) * 4;
    float acc[4][4] = {};

    for (int kt = 0; kt < 1024; kt += 16) {
        const float4 a = load4(A + (size_t)(row0 + lrow) * 1024 + kt + lk);
        const float4 b = load4(W + (size_t)(col0 + lrow) * 1024 + kt + lk);
        As[lk + 0][lrow] = a.x; As[lk + 1][lrow] = a.y;
        As[lk + 2][lrow] = a.z; As[lk + 3][lrow] = a.w;
        Bs[lk + 0][lrow] = b.x; Bs[lk + 1][lrow] = b.y;
        Bs[lk + 2][lrow] = b.z; Bs[lk + 3][lrow] = b.w;
        __syncthreads();
#pragma unroll
        for (int kk = 0; kk < 16; kk++) {
            const float4 aa = *(const float4*)&As[kk][ty * 4];
            const float4 bb = *(const float4*)&Bs[kk][tx * 4];
            const float avv[4] = {aa.x, aa.y, aa.z, aa.w};
            const float bvv[4] = {bb.x, bb.y, bb.z, bb.w};
#pragma unroll
            for (int i = 0; i < 4; i++)
#pragma unroll
                for (int j = 0; j < 4; j++) acc[i][j] += avv[i] * bvv[j];
        }
        __syncthreads();
    }

#pragma unroll
    for (int i = 0; i < 4; i++) {
        const int r = row0 + ty * 4 + i;
#pragma unroll
        for (int j = 0; j < 4; j++) {
            const int c = col0 + tx * 4 + j;
            stf(out + (size_t)r * 1024 + c, acc[i][j] + bias_f[c]);
        }
    }
}

// ---------------------------------------------------------------------------
extern "C" void kernel_launch(void* const* d_in, const int* in_sizes, int n_in,
                              void* d_out, int out_size, void* d_ws, size_t ws_size,
                              hipStream_t stream)
{
    // Workspace layout: bf16 q_hat|k_hat|v|o (4 x 16 MiB), then fp32 small
    // buffer (4128 floats), then int flag.
    const size_t SEG = (size_t)8 * 16 * 1024 * 64;   // 8388608 elements each
    bf16* qn = (bf16*)d_ws;
    bf16* kn = qn + SEG;
    bf16* vv = kn + SEG;
    bf16* ow = vv + SEG;
    float* smallf = (float*)(ow + SEG);              // 4128 floats
    int*   flag   = (int*)(smallf + 4128);

    // 0) detect input dtype (1 = fp32, 0 = bf16)
    detect_kernel<<<1, 256, 0, stream>>>((const unsigned short*)d_in[0], flag);

    // 0b) small conversions (biases, exp(min(ls)), head_scale) -> fp32 ws
    convert_small_kernel<bf16><<<1, 256, 0, stream>>>(flag, 0,
        (const bf16*)d_in[2], (const bf16*)d_in[6], (const bf16*)d_in[3], (const bf16*)d_in[4], smallf);
    convert_small_kernel<float><<<1, 256, 0, stream>>>(flag, 1,
        (const float*)d_in[2], (const float*)d_in[6], (const float*)d_in[3], (const float*)d_in[4], smallf);

    // 1) qkv = x @ W^T + b, scattered to (N,H,L,hd) bf16
    const dim3 qkv_grid(3072 / 64, 8192 / 64);
    qkv_gemm_kernel<bf16><<<qkv_grid, 256, 0, stream>>>(flag, 0,
        (const bf16*)d_in[0], (const bf16*)d_in[1], smallf, qn, kn, vv);
    qkv_gemm_kernel<float><<<qkv_grid, 256, 0, stream>>>(flag, 1,
        (const float*)d_in[0], (const float*)d_in[1], smallf, qn, kn, vv);

    // 2) L2-normalize q and k rows (contiguous 2*SEG/64 rows)
    normalize_kernel<<<dim3((2 * 8 * 16 * 1024) / 4), 256, 0, stream>>>(qn);

    // 3) scaled-cosine softmax attention -> o in (L*N, C) bf16
    attn_kernel<<<dim3(8 * 16 * 256), 256, 0, stream>>>(qn, kn, vv, smallf, ow);

    // 4) out = o @ out_w^T + out_b
    const dim3 out_grid(1024 / 64, 8192 / 64);
    out_gemm_kernel<bf16><<<out_grid, 256, 0, stream>>>(flag, 0,
        ow, (const bf16*)d_in[5], smallf + 3072, (bf16*)d_out);
    out_gemm_kernel<float><<<out_grid, 256, 0, stream>>>(flag, 1,
        ow, (const float*)d_in[5], smallf + 3072, (float*)d_out);
}

// Round 4
// 1147.330 us; speedup vs baseline: 3.5699x; 3.5699x over previous
//
#include <hip/hip_runtime.h>
#include <hip/hip_bf16.h>

typedef __hip_bfloat16 bf16;
typedef __attribute__((ext_vector_type(8))) short bf16x8;
typedef __attribute__((ext_vector_type(4))) float f32x4;

// Problem constants: x (L=1024, N=8, C=1024), H=16 heads, hd=64
#define LOGIT_MAX 4.6051702f   // log(1/0.01)

// exact bf16 -> fp32 from packed uint halves (little-endian: lo = even elem)
__device__ __forceinline__ float bflo(unsigned u) {
    union { unsigned x; float f; } c; c.x = u << 16; return c.f;
}
__device__ __forceinline__ float bfhi(unsigned u) {
    union { unsigned x; float f; } c; c.x = u & 0xffff0000u; return c.f;
}

__device__ __forceinline__ float ldf(const float* p) { return *p; }
__device__ __forceinline__ float ldf(const bf16*  p) { return __bfloat162float(*p); }

__device__ __forceinline__ float4 load4(const float* p) { return *(const float4*)p; }
__device__ __forceinline__ float4 load4(const bf16* p) {
    const uint2 u = *(const uint2*)p;
    return make_float4(bflo(u.x), bfhi(u.x), bflo(u.y), bfhi(u.y));
}

__device__ __forceinline__ void stf(float* p, float v) { *p = v; }
__device__ __forceinline__ void stf(bf16*  p, float v) { *p = __float2bfloat16(v); }

// ---------------------------------------------------------------------------
// Kernel 0: dtype detection (1 = fp32 inputs, 0 = bf16 inputs).
// ---------------------------------------------------------------------------
__global__ void detect_kernel(const unsigned short* __restrict__ x, int* __restrict__ flag)
{
    __shared__ int cnt;
    if (threadIdx.x == 0) cnt = 0;
    __syncthreads();
    int c = 0;
    for (int i = threadIdx.x; i < 4096; i += 256) {
        const unsigned e = (x[i] >> 7) & 0xFF;
        if (e >= 0x90) c++;
    }
    atomicAdd(&cnt, c);
    __syncthreads();
    if (threadIdx.x == 0) *flag = (cnt > 64) ? 1 : 0;
}

// ---------------------------------------------------------------------------
// Kernel 0b: small conversions -> fp32 ws: [0,3072) in_proj_bias,
// [3072,4096) out_b, [4096,4112) exp(min(ls,MAX)), [4112,4128) head_scale.
// ---------------------------------------------------------------------------
template <typename T>
__global__ void convert_small_kernel(const int* __restrict__ flag, int mode,
                                     const T* __restrict__ b_in, const T* __restrict__ out_b,
                                     const T* __restrict__ ls, const T* __restrict__ hs,
                                     float* __restrict__ dst)
{
    if (*flag != mode) return;
    for (int idx = threadIdx.x; idx < 4128; idx += 256) {
        float v;
        if (idx < 3072)      v = ldf(b_in + idx);
        else if (idx < 4096) v = ldf(out_b + (idx - 3072));
        else if (idx < 4112) v = expf(fminf(ldf(ls + (idx - 4096)), LOGIT_MAX));
        else                 v = ldf(hs + (idx - 4112));
        dst[idx] = v;
    }
}

// ---------------------------------------------------------------------------
// Kernel 1: QKV projection. q,k -> (N*H, L, 64); v -> TRANSPOSED (N*H, 64, L)
// so the attention kernel can stage V-tiles with coalesced loads.
// ---------------------------------------------------------------------------
template <typename T>
__global__ __launch_bounds__(256) void qkv_gemm_kernel(
    const int* __restrict__ flag, int mode,
    const T* __restrict__ X, const T* __restrict__ W,
    const float* __restrict__ bias_f,
    bf16* __restrict__ q, bf16* __restrict__ k, bf16* __restrict__ vt)
{
    if (*flag != mode) return;
    __shared__ float As[16][68];
    __shared__ float Bs[16][68];
    const int tid  = threadIdx.x;
    const int tx   = tid & 15, ty = tid >> 4;
    const int row0 = blockIdx.y * 64;
    const int col0 = blockIdx.x * 64;
    const int lrow = tid >> 2;
    const int lk   = (tid & 3) * 4;
    float acc[4][4] = {};

    for (int kt = 0; kt < 1024; kt += 16) {
        const float4 a = load4(X + (size_t)(row0 + lrow) * 1024 + kt + lk);
        const float4 b = load4(W + (size_t)(col0 + lrow) * 1024 + kt + lk);
        As[lk + 0][lrow] = a.x; As[lk + 1][lrow] = a.y;
        As[lk + 2][lrow] = a.z; As[lk + 3][lrow] = a.w;
        Bs[lk + 0][lrow] = b.x; Bs[lk + 1][lrow] = b.y;
        Bs[lk + 2][lrow] = b.z; Bs[lk + 3][lrow] = b.w;
        __syncthreads();
#pragma unroll
        for (int kk = 0; kk < 16; kk++) {
            const float4 aa = *(const float4*)&As[kk][ty * 4];
            const float4 bb = *(const float4*)&Bs[kk][tx * 4];
            const float avv[4] = {aa.x, aa.y, aa.z, aa.w};
            const float bvv[4] = {bb.x, bb.y, bb.z, bb.w};
#pragma unroll
            for (int i = 0; i < 4; i++)
#pragma unroll
                for (int j = 0; j < 4; j++) acc[i][j] += avv[i] * bvv[j];
        }
        __syncthreads();
    }

#pragma unroll
    for (int i = 0; i < 4; i++) {
        const int r = row0 + ty * 4 + i;
        const int l = r >> 3, n = r & 7;
#pragma unroll
        for (int j = 0; j < 4; j++) {
            const int c   = col0 + tx * 4 + j;
            const float val = acc[i][j] + bias_f[c];
            const int part = c >> 10;
            const int cc   = c & 1023;
            const int h = cc >> 6, d = cc & 63;
            const bf16 bv = __float2bfloat16(val);
            if (part < 2) {
                bf16* dst = (part == 0) ? q : k;
                dst[((size_t)((n * 16 + h) * 1024 + l)) * 64 + d] = bv;
            } else {
                vt[((size_t)((n * 16 + h) * 64 + d)) * 1024 + l] = bv;
            }
        }
    }
}

// ---------------------------------------------------------------------------
// Kernel 2: L2-normalize rows of 64 (q then k contiguous).
// ---------------------------------------------------------------------------
__global__ __launch_bounds__(256) void normalize_kernel(bf16* __restrict__ qk)
{
    const int row  = blockIdx.x * 4 + (threadIdx.x >> 6);
    const int lane = threadIdx.x & 63;
    bf16* p = qk + (size_t)row * 64;
    const float val = __bfloat162float(p[lane]);
    float ss = val * val;
#pragma unroll
    for (int off = 32; off > 0; off >>= 1) ss += __shfl_down(ss, off, 64);
    ss = __shfl(ss, 0, 64);
    const float dn = fmaxf(sqrtf(ss), 1e-12f);
    p[lane] = __float2bfloat16(val / dn);
}

// ---------------------------------------------------------------------------
// Kernel 3: MFMA flash attention. 1 block = 4 waves = 64 q-rows of one (n,h).
// Loop over 16 K-tiles of 64 keys: stage K (64x64) and Vt (64d x 64key) in
// LDS, S = Q K^T via mfma_f32_16x16x32_bf16, online softmax (per-row m,l in
// regs, rows = quad*4+reg), P via wave-private LDS slab (C->A layout), PV
// MFMA accumulate. Layouts: A m=lane&15,k=quad*8+j; B n=lane&15,k=quad*8+j;
// C/D col=lane&15,row=quad*4+reg (m89/m91/m120-verified).
// ---------------------------------------------------------------------------
__global__ __launch_bounds__(256) void attn_mfma_kernel(
    const bf16* __restrict__ q, const bf16* __restrict__ k,
    const bf16* __restrict__ vt, const float* __restrict__ scale_f,
    bf16* __restrict__ o)
{
    __shared__ bf16 K_lds[64][72];       // [key][d], pad 8 keeps 16B rows
    __shared__ bf16 Vt_lds[64][72];      // [d][key]
    __shared__ bf16 P_lds[4][16][72];    // wave-private [qrow][key]

    const int bid  = blockIdx.x;
    const int qt   = bid & 15;           // q-tile (64 rows) within (n,h)
    const int nh   = bid >> 4;           // 0..127
    const int h    = nh & 15;
    const int n    = nh >> 4;
    const int tid  = threadIdx.x;
    const int w    = tid >> 6;
    const int lane = tid & 63;
    const int l16  = lane & 15;
    const int quad = lane >> 4;

    const size_t base = (size_t)nh * (1024 * 64);    // q,k and vt bases equal

    const float ls = scale_f[4096 + h];
    const float hs = scale_f[4112 + h];

    // Q fragments (persist whole kernel): rows qt*64 + w*16 + l16
    const int qrow = qt * 64 + w * 16 + l16;
    const bf16* qp = q + base + (size_t)qrow * 64 + quad * 8;
    const bf16x8 qf0 = *(const bf16x8*)(qp);        // d = quad*8+j
    const bf16x8 qf1 = *(const bf16x8*)(qp + 32);   // d = 32+quad*8+j

    f32x4 o_acc[4] = {};                 // d-subtiles, C layout
    float m_r[4] = {-1e30f, -1e30f, -1e30f, -1e30f};
    float l_r[4] = {};

    const int srow = tid >> 2;           // staging: row 0..63
    const int sseg = (tid & 3) * 16;     // 16-elem segment

    for (int j0 = 0; j0 < 1024; j0 += 64) {
        __syncthreads();                 // prior iter's readers done
        {
            const uint4* kg = (const uint4*)(k + base + (size_t)(j0 + srow) * 64 + sseg);
            const uint4 k0 = kg[0], k1 = kg[1];
            *(uint4*)&K_lds[srow][sseg]     = k0;
            *(uint4*)&K_lds[srow][sseg + 8] = k1;
            const uint4* vg = (const uint4*)(vt + base + (size_t)srow * 1024 + j0 + sseg);
            const uint4 v0 = vg[0], v1 = vg[1];
            *(uint4*)&Vt_lds[srow][sseg]     = v0;
            *(uint4*)&Vt_lds[srow][sseg + 8] = v1;
        }
        __syncthreads();

        // S = Q K^T, scaled by ls; 4 key-subtiles of 16
        f32x4 s_sub[4];
#pragma unroll
        for (int s = 0; s < 4; s++) {
            f32x4 acc = {};
            const bf16x8 kf0 = *(const bf16x8*)&K_lds[s * 16 + l16][quad * 8];
            const bf16x8 kf1 = *(const bf16x8*)&K_lds[s * 16 + l16][32 + quad * 8];
            acc = __builtin_amdgcn_mfma_f32_16x16x32_bf16(qf0, kf0, acc, 0, 0, 0);
            acc = __builtin_amdgcn_mfma_f32_16x16x32_bf16(qf1, kf1, acc, 0, 0, 0);
            s_sub[s] = acc * ls;
        }

        // online softmax: row r_global = quad*4+r, cols s*16+l16
        float alpha[4];
#pragma unroll
        for (int r = 0; r < 4; r++) {
            float v = fmaxf(fmaxf(s_sub[0][r], s_sub[1][r]),
                            fmaxf(s_sub[2][r], s_sub[3][r]));
            v = fmaxf(v, __shfl_xor(v, 1));
            v = fmaxf(v, __shfl_xor(v, 2));
            v = fmaxf(v, __shfl_xor(v, 4));
            v = fmaxf(v, __shfl_xor(v, 8));
            const float mn = fmaxf(m_r[r], v);
            alpha[r] = __expf(m_r[r] - mn);
            m_r[r] = mn;
        }
#pragma unroll
        for (int s = 0; s < 4; s++) {
#pragma unroll
            for (int r = 0; r < 4; r++) {
                const float p = __expf(s_sub[s][r] - m_r[r]);
                s_sub[s][r] = p;
                P_lds[w][quad * 4 + r][s * 16 + l16] = __float2bfloat16(p);
            }
        }
#pragma unroll
        for (int r = 0; r < 4; r++) {
            float v = s_sub[0][r] + s_sub[1][r] + s_sub[2][r] + s_sub[3][r];
            v += __shfl_xor(v, 1);
            v += __shfl_xor(v, 2);
            v += __shfl_xor(v, 4);
            v += __shfl_xor(v, 8);
            l_r[r] = l_r[r] * alpha[r] + v;
            o_acc[0][r] *= alpha[r];
            o_acc[1][r] *= alpha[r];
            o_acc[2][r] *= alpha[r];
            o_acc[3][r] *= alpha[r];
        }

        // PV: A = P (k=key), B = Vt (n=d, k=key)
        const bf16x8 pf0 = *(const bf16x8*)&P_lds[w][l16][quad * 8];
        const bf16x8 pf1 = *(const bf16x8*)&P_lds[w][l16][32 + quad * 8];
#pragma unroll
        for (int ds = 0; ds < 4; ds++) {
            const bf16x8 vf0 = *(const bf16x8*)&Vt_lds[ds * 16 + l16][quad * 8];
            const bf16x8 vf1 = *(const bf16x8*)&Vt_lds[ds * 16 + l16][32 + quad * 8];
            o_acc[ds] = __builtin_amdgcn_mfma_f32_16x16x32_bf16(pf0, vf0, o_acc[ds], 0, 0, 0);
            o_acc[ds] = __builtin_amdgcn_mfma_f32_16x16x32_bf16(pf1, vf1, o_acc[ds], 0, 0, 0);
        }
    }

    // epilogue: O * hs / l, store to o (L*N, C): row l*8+n, col h*64+d
#pragma unroll
    for (int r = 0; r < 4; r++) {
        const float inv = hs / l_r[r];
        const int row_l = qt * 64 + w * 16 + quad * 4 + r;
        bf16* dst = o + ((size_t)row_l * 8 + n) * 1024 + h * 64 + l16;
#pragma unroll
        for (int ds = 0; ds < 4; ds++)
            dst[ds * 16] = __float2bfloat16(o_acc[ds][r] * inv);
    }
}

// ---------------------------------------------------------------------------
// Kernel 4: out projection. out[r][c] = sum_k A[r][k]*W[c][k] + b[c].
// ---------------------------------------------------------------------------
template <typename T>
__global__ __launch_bounds__(256) void out_gemm_kernel(
    const int* __restrict__ flag, int mode,
    const bf16* __restrict__ A, const T* __restrict__ W,
    const float* __restrict__ bias_f, T* __restrict__ out)
{
    if (*flag != mode) return;
    __shared__ float As[16][68];
    __shared__ float Bs[16][68];
    const int tid  = threadIdx.x;
    const int tx   = tid & 15, ty = tid >> 4;
    const int row0 = blockIdx.y * 64;
    const int col0 = blockIdx.x * 64;
    const int lrow = tid >> 2;
    const int lk   = (tid & 3) * 4;
    float acc[4][4] = {};

    for (int kt = 0; kt < 1024; kt += 16) {
        const float4 a = load4(A + (size_t)(row0 + lrow) * 1024 + kt + lk);
        const float4 b = load4(W + (size_t)(col0 + lrow) * 1024 + kt + lk);
        As[lk + 0][lrow] = a.x; As[lk + 1][lrow] = a.y;
        As[lk + 2][lrow] = a.z; As[lk + 3][lrow] = a.w;
        Bs[lk + 0][lrow] = b.x; Bs[lk + 1][lrow] = b.y;
        Bs[lk + 2][lrow] = b.z; Bs[lk + 3][lrow] = b.w;
        __syncthreads();
#pragma unroll
        for (int kk = 0; kk < 16; kk++) {
            const float4 aa = *(const float4*)&As[kk][ty * 4];
            const float4 bb = *(const float4*)&Bs[kk][tx * 4];
            const float avv[4] = {aa.x, aa.y, aa.z, aa.w};
            const float bvv[4] = {bb.x, bb.y, bb.z, bb.w};
#pragma unroll
            for (int i = 0; i < 4; i++)
#pragma unroll
                for (int j = 0; j < 4; j++) acc[i][j] += avv[i] * bvv[j];
        }
        __syncthreads();
    }

#pragma unroll
    for (int i = 0; i < 4; i++) {
        const int r = row0 + ty * 4 + i;
#pragma unroll
        for (int j = 0; j < 4; j++) {
            const int c = col0 + tx * 4 + j;
            stf(out + (size_t)r * 1024 + c, acc[i][j] + bias_f[c]);
        }
    }
}

// ---------------------------------------------------------------------------
extern "C" void kernel_launch(void* const* d_in, const int* in_sizes, int n_in,
                              void* d_out, int out_size, void* d_ws, size_t ws_size,
                              hipStream_t stream)
{
    const size_t SEG = (size_t)8 * 16 * 1024 * 64;   // 8388608 elems
    bf16* qn = (bf16*)d_ws;
    bf16* kn = qn + SEG;
    bf16* vt = kn + SEG;
    bf16* ow = vt + SEG;
    float* smallf = (float*)(ow + SEG);              // 4128 floats
    int*   flag   = (int*)(smallf + 4128);

    detect_kernel<<<1, 256, 0, stream>>>((const unsigned short*)d_in[0], flag);

    convert_small_kernel<bf16><<<1, 256, 0, stream>>>(flag, 0,
        (const bf16*)d_in[2], (const bf16*)d_in[6], (const bf16*)d_in[3], (const bf16*)d_in[4], smallf);
    convert_small_kernel<float><<<1, 256, 0, stream>>>(flag, 1,
        (const float*)d_in[2], (const float*)d_in[6], (const float*)d_in[3], (const float*)d_in[4], smallf);

    const dim3 qkv_grid(3072 / 64, 8192 / 64);
    qkv_gemm_kernel<bf16><<<qkv_grid, 256, 0, stream>>>(flag, 0,
        (const bf16*)d_in[0], (const bf16*)d_in[1], smallf, qn, kn, vt);
    qkv_gemm_kernel<float><<<qkv_grid, 256, 0, stream>>>(flag, 1,
        (const float*)d_in[0], (const float*)d_in[1], smallf, qn, kn, vt);

    normalize_kernel<<<dim3((2 * 8 * 16 * 1024) / 4), 256, 0, stream>>>(qn);

    attn_mfma_kernel<<<dim3(128 * 16), 256, 0, stream>>>(qn, kn, vt, smallf, ow);

    const dim3 out_grid(1024 / 64, 8192 / 64);
    out_gemm_kernel<bf16><<<out_grid, 256, 0, stream>>>(flag, 0,
        ow, (const bf16*)d_in[5], smallf + 3072, (bf16*)d_out);
    out_gemm_kernel<float><<<out_grid, 256, 0, stream>>>(flag, 1,
        ow, (const float*)d_in[5], smallf + 3072, (float*)d_out);
}

// Round 5
// 377.584 us; speedup vs baseline: 10.8476x; 3.0386x over previous
//
#include <hip/hip_runtime.h>
#include <hip/hip_bf16.h>

typedef __hip_bfloat16 bf16;
typedef __attribute__((ext_vector_type(8))) short bf16x8;
typedef __attribute__((ext_vector_type(4))) float f32x4;

// Problem constants: x (L=1024, N=8, C=1024), H=16 heads, hd=64
#define LOGIT_MAX 4.6051702f   // log(1/0.01)

__device__ __forceinline__ float bflo(unsigned u) {
    union { unsigned x; float f; } c; c.x = u << 16; return c.f;
}
__device__ __forceinline__ float bfhi(unsigned u) {
    union { unsigned x; float f; } c; c.x = u & 0xffff0000u; return c.f;
}

__device__ __forceinline__ float ldf(const float* p) { return *p; }
__device__ __forceinline__ float ldf(const bf16*  p) { return __bfloat162float(*p); }

__device__ __forceinline__ float4 load4(const float* p) { return *(const float4*)p; }
__device__ __forceinline__ float4 load4(const bf16* p) {
    const uint2 u = *(const uint2*)p;
    return make_float4(bflo(u.x), bfhi(u.x), bflo(u.y), bfhi(u.y));
}

__device__ __forceinline__ void stf(float* p, float v) { *p = v; }
__device__ __forceinline__ void stf(bf16*  p, float v) { *p = __float2bfloat16(v); }

__device__ __forceinline__ void store4bf(bf16* p, float4 v) {
    union { bf16 b[4]; uint2 u; } t;
    t.b[0] = __float2bfloat16(v.x); t.b[1] = __float2bfloat16(v.y);
    t.b[2] = __float2bfloat16(v.z); t.b[3] = __float2bfloat16(v.w);
    *(uint2*)p = t.u;
}

// async global->LDS, 16B per lane; lds base must be wave-uniform, lane i's
// data lands at lds + i*16B (m97/m104-verified semantics).
__device__ __forceinline__ void async16(const bf16* g, bf16* lds) {
    __builtin_amdgcn_global_load_lds(
        (const __attribute__((address_space(1))) void*)g,
        (__attribute__((address_space(3))) void*)lds, 16, 0, 0);
}

// Stage 16 rows x 32 elems (64B) of a K-contiguous matrix into LDS with
// chunk swizzle: stored chunk c at row r holds global chunk c^(r&3).
// One instruction per wave: lane = r*4+c.
__device__ __forceinline__ void stage16rows(const bf16* __restrict__ g, bf16* lds, int lane) {
    const int r  = lane >> 2, c = lane & 3;
    const int cg = c ^ (r & 3);
    async16(g + r * 1024 + cg * 8, lds);
}

// ---------------------------------------------------------------------------
// Kernel 0: dtype detection (1 = fp32 inputs, 0 = bf16 inputs).
// ---------------------------------------------------------------------------
__global__ void detect_kernel(const unsigned short* __restrict__ x, int* __restrict__ flag)
{
    __shared__ int cnt;
    if (threadIdx.x == 0) cnt = 0;
    __syncthreads();
    int c = 0;
    for (int i = threadIdx.x; i < 4096; i += 256) {
        const unsigned e = (x[i] >> 7) & 0xFF;
        if (e >= 0x90) c++;
    }
    atomicAdd(&cnt, c);
    __syncthreads();
    if (threadIdx.x == 0) *flag = (cnt > 64) ? 1 : 0;
}

// ---------------------------------------------------------------------------
// Kernel 0b: small conversions -> fp32 ws: [0,3072) in_proj_bias,
// [3072,4096) out_b, [4096,4112) exp(min(ls,MAX)), [4112,4128) head_scale.
// ---------------------------------------------------------------------------
template <typename T>
__global__ void convert_small_kernel(const int* __restrict__ flag, int mode,
                                     const T* __restrict__ b_in, const T* __restrict__ out_b,
                                     const T* __restrict__ ls, const T* __restrict__ hs,
                                     float* __restrict__ dst)
{
    if (*flag != mode) return;
    for (int idx = threadIdx.x; idx < 4128; idx += 256) {
        float v;
        if (idx < 3072)      v = ldf(b_in + idx);
        else if (idx < 4096) v = ldf(out_b + (idx - 3072));
        else if (idx < 4112) v = expf(fminf(ldf(ls + (idx - 4096)), LOGIT_MAX));
        else                 v = ldf(hs + (idx - 4112));
        dst[idx] = v;
    }
}

// ---------------------------------------------------------------------------
// Kernel 0c: convert x / in_proj_weight / out_w to bf16 ws copies (gated).
// ---------------------------------------------------------------------------
template <typename T>
__global__ __launch_bounds__(256) void convert_inputs_kernel(
    const int* __restrict__ flag, int mode,
    const T* __restrict__ x, const T* __restrict__ w_in, const T* __restrict__ out_w,
    bf16* __restrict__ xb, bf16* __restrict__ wb, bf16* __restrict__ owb)
{
    if (*flag != mode) return;
    const size_t NX = 8388608, NW = 3145728, NO = 1048576;
    const size_t t0   = ((size_t)blockIdx.x * 256 + threadIdx.x) * 4;
    const size_t step = (size_t)gridDim.x * 256 * 4;
    for (size_t i = t0; i < NX; i += step) store4bf(xb + i, load4(x + i));
    for (size_t i = t0; i < NW; i += step) store4bf(wb + i, load4(w_in + i));
    for (size_t i = t0; i < NO; i += step) store4bf(owb + i, load4(out_w + i));
}

// ---------------------------------------------------------------------------
// Kernel 1: MFMA QKV projection. C[8192x3072] = X[8192x1024] . W[3072x1024]^T
// 128x128 block tile, BK=32, 4 waves (2x2), 4x4 mfma_f32_16x16x32_bf16/wave.
// global_load_lds(16B) staging, XOR chunk swizzle for conflict-lite ds_reads.
// Epilogue scatters: q,k -> (N*H, L, 64); v -> (N*H, 64, L) transposed.
// ---------------------------------------------------------------------------
__global__ __launch_bounds__(256) void qkv_gemm_mfma_kernel(
    const bf16* __restrict__ X, const bf16* __restrict__ W,
    const float* __restrict__ bias_f,
    bf16* __restrict__ q, bf16* __restrict__ k, bf16* __restrict__ vt)
{
    __shared__ bf16 A_lds[128 * 32];
    __shared__ bf16 B_lds[128 * 32];
    const int tid  = threadIdx.x;
    const int w    = tid >> 6;
    const int lane = tid & 63;
    const int l16  = lane & 15, quad = lane >> 4;
    const int wm   = w >> 1, wn = w & 1;
    const int row0 = blockIdx.y * 128;
    const int col0 = blockIdx.x * 128;

    f32x4 acc[4][4] = {};

    for (int kt = 0; kt < 1024; kt += 32) {
        __syncthreads();
        {
            const bf16* ga = X + (size_t)(row0 + w * 32) * 1024 + kt;
            stage16rows(ga,             &A_lds[(w * 32) * 32], lane);
            stage16rows(ga + 16 * 1024, &A_lds[(w * 32 + 16) * 32], lane);
            const bf16* gb = W + (size_t)(col0 + w * 32) * 1024 + kt;
            stage16rows(gb,             &B_lds[(w * 32) * 32], lane);
            stage16rows(gb + 16 * 1024, &B_lds[(w * 32 + 16) * 32], lane);
        }
        __syncthreads();

        bf16x8 af[4], bf[4];
#pragma unroll
        for (int mt = 0; mt < 4; mt++) {
            const int row = wm * 64 + mt * 16 + l16;
            af[mt] = *(const bf16x8*)&A_lds[row * 32 + ((quad ^ (row & 3)) * 8)];
        }
#pragma unroll
        for (int nt = 0; nt < 4; nt++) {
            const int row = wn * 64 + nt * 16 + l16;
            bf[nt] = *(const bf16x8*)&B_lds[row * 32 + ((quad ^ (row & 3)) * 8)];
        }
#pragma unroll
        for (int mt = 0; mt < 4; mt++)
#pragma unroll
            for (int nt = 0; nt < 4; nt++)
                acc[mt][nt] = __builtin_amdgcn_mfma_f32_16x16x32_bf16(af[mt], bf[nt], acc[mt][nt], 0, 0, 0);
    }

    // epilogue: C row r -> (l = r>>3, n = r&7); col c -> (part, h, d)
#pragma unroll
    for (int mt = 0; mt < 4; mt++) {
        const int rbase = row0 + wm * 64 + mt * 16 + quad * 4;
#pragma unroll
        for (int nt = 0; nt < 4; nt++) {
            const int c = col0 + wn * 64 + nt * 16 + l16;
            const int part = c >> 10, cc = c & 1023;
            const int h = cc >> 6, d = cc & 63;
            const float bias = bias_f[c];
#pragma unroll
            for (int rg = 0; rg < 4; rg++) {
                const int r = rbase + rg;
                const int l = r >> 3, n = r & 7;
                const bf16 bv = __float2bfloat16(acc[mt][nt][rg] + bias);
                if (part < 2) {
                    bf16* dst = (part == 0) ? q : k;
                    dst[((size_t)((n * 16 + h) * 1024 + l)) * 64 + d] = bv;
                } else {
                    vt[((size_t)((n * 16 + h) * 64 + d)) * 1024 + l] = bv;
                }
            }
        }
    }
}

// ---------------------------------------------------------------------------
// Kernel 2: L2-normalize rows of 64 (q then k contiguous).
// ---------------------------------------------------------------------------
__global__ __launch_bounds__(256) void normalize_kernel(bf16* __restrict__ qk)
{
    const int row  = blockIdx.x * 4 + (threadIdx.x >> 6);
    const int lane = threadIdx.x & 63;
    bf16* p = qk + (size_t)row * 64;
    const float val = __bfloat162float(p[lane]);
    float ss = val * val;
#pragma unroll
    for (int off = 32; off > 0; off >>= 1) ss += __shfl_down(ss, off, 64);
    ss = __shfl(ss, 0, 64);
    const float dn = fmaxf(sqrtf(ss), 1e-12f);
    p[lane] = __float2bfloat16(val / dn);
}

// ---------------------------------------------------------------------------
// Kernel 3: MFMA flash attention (unchanged from R4 — passed, ~200 us).
// ---------------------------------------------------------------------------
__global__ __launch_bounds__(256) void attn_mfma_kernel(
    const bf16* __restrict__ q, const bf16* __restrict__ k,
    const bf16* __restrict__ vt, const float* __restrict__ scale_f,
    bf16* __restrict__ o)
{
    __shared__ bf16 K_lds[64][72];
    __shared__ bf16 Vt_lds[64][72];
    __shared__ bf16 P_lds[4][16][72];

    const int bid  = blockIdx.x;
    const int qt   = bid & 15;
    const int nh   = bid >> 4;
    const int h    = nh & 15;
    const int n    = nh >> 4;
    const int tid  = threadIdx.x;
    const int w    = tid >> 6;
    const int lane = tid & 63;
    const int l16  = lane & 15;
    const int quad = lane >> 4;

    const size_t base = (size_t)nh * (1024 * 64);

    const float ls = scale_f[4096 + h];
    const float hs = scale_f[4112 + h];

    const int qrow = qt * 64 + w * 16 + l16;
    const bf16* qp = q + base + (size_t)qrow * 64 + quad * 8;
    const bf16x8 qf0 = *(const bf16x8*)(qp);
    const bf16x8 qf1 = *(const bf16x8*)(qp + 32);

    f32x4 o_acc[4] = {};
    float m_r[4] = {-1e30f, -1e30f, -1e30f, -1e30f};
    float l_r[4] = {};

    const int srow = tid >> 2;
    const int sseg = (tid & 3) * 16;

    for (int j0 = 0; j0 < 1024; j0 += 64) {
        __syncthreads();
        {
            const uint4* kg = (const uint4*)(k + base + (size_t)(j0 + srow) * 64 + sseg);
            const uint4 k0 = kg[0], k1 = kg[1];
            *(uint4*)&K_lds[srow][sseg]     = k0;
            *(uint4*)&K_lds[srow][sseg + 8] = k1;
            const uint4* vg = (const uint4*)(vt + base + (size_t)srow * 1024 + j0 + sseg);
            const uint4 v0 = vg[0], v1 = vg[1];
            *(uint4*)&Vt_lds[srow][sseg]     = v0;
            *(uint4*)&Vt_lds[srow][sseg + 8] = v1;
        }
        __syncthreads();

        f32x4 s_sub[4];
#pragma unroll
        for (int s = 0; s < 4; s++) {
            f32x4 acc = {};
            const bf16x8 kf0 = *(const bf16x8*)&K_lds[s * 16 + l16][quad * 8];
            const bf16x8 kf1 = *(const bf16x8*)&K_lds[s * 16 + l16][32 + quad * 8];
            acc = __builtin_amdgcn_mfma_f32_16x16x32_bf16(qf0, kf0, acc, 0, 0, 0);
            acc = __builtin_amdgcn_mfma_f32_16x16x32_bf16(qf1, kf1, acc, 0, 0, 0);
            s_sub[s] = acc * ls;
        }

        float alpha[4];
#pragma unroll
        for (int r = 0; r < 4; r++) {
            float v = fmaxf(fmaxf(s_sub[0][r], s_sub[1][r]),
                            fmaxf(s_sub[2][r], s_sub[3][r]));
            v = fmaxf(v, __shfl_xor(v, 1));
            v = fmaxf(v, __shfl_xor(v, 2));
            v = fmaxf(v, __shfl_xor(v, 4));
            v = fmaxf(v, __shfl_xor(v, 8));
            const float mn = fmaxf(m_r[r], v);
            alpha[r] = __expf(m_r[r] - mn);
            m_r[r] = mn;
        }
#pragma unroll
        for (int s = 0; s < 4; s++) {
#pragma unroll
            for (int r = 0; r < 4; r++) {
                const float p = __expf(s_sub[s][r] - m_r[r]);
                s_sub[s][r] = p;
                P_lds[w][quad * 4 + r][s * 16 + l16] = __float2bfloat16(p);
            }
        }
#pragma unroll
        for (int r = 0; r < 4; r++) {
            float v = s_sub[0][r] + s_sub[1][r] + s_sub[2][r] + s_sub[3][r];
            v += __shfl_xor(v, 1);
            v += __shfl_xor(v, 2);
            v += __shfl_xor(v, 4);
            v += __shfl_xor(v, 8);
            l_r[r] = l_r[r] * alpha[r] + v;
            o_acc[0][r] *= alpha[r];
            o_acc[1][r] *= alpha[r];
            o_acc[2][r] *= alpha[r];
            o_acc[3][r] *= alpha[r];
        }

        const bf16x8 pf0 = *(const bf16x8*)&P_lds[w][l16][quad * 8];
        const bf16x8 pf1 = *(const bf16x8*)&P_lds[w][l16][32 + quad * 8];
#pragma unroll
        for (int ds = 0; ds < 4; ds++) {
            const bf16x8 vf0 = *(const bf16x8*)&Vt_lds[ds * 16 + l16][quad * 8];
            const bf16x8 vf1 = *(const bf16x8*)&Vt_lds[ds * 16 + l16][32 + quad * 8];
            o_acc[ds] = __builtin_amdgcn_mfma_f32_16x16x32_bf16(pf0, vf0, o_acc[ds], 0, 0, 0);
            o_acc[ds] = __builtin_amdgcn_mfma_f32_16x16x32_bf16(pf1, vf1, o_acc[ds], 0, 0, 0);
        }
    }

#pragma unroll
    for (int r = 0; r < 4; r++) {
        const float inv = hs / l_r[r];
        const int row_l = qt * 64 + w * 16 + quad * 4 + r;
        bf16* dst = o + ((size_t)row_l * 8 + n) * 1024 + h * 64 + l16;
#pragma unroll
        for (int ds = 0; ds < 4; ds++)
            dst[ds * 16] = __float2bfloat16(o_acc[ds][r] * inv);
    }
}

// ---------------------------------------------------------------------------
// Kernel 4: MFMA out projection. out[8192x1024] = A . W^T + b.
// Same structure as kernel 1; output store type templated (gated by flag).
// ---------------------------------------------------------------------------
template <typename TOUT>
__global__ __launch_bounds__(256) void out_gemm_mfma_kernel(
    const int* __restrict__ flag, int mode,
    const bf16* __restrict__ A, const bf16* __restrict__ B,
    const float* __restrict__ bias_f, TOUT* __restrict__ out)
{
    if (*flag != mode) return;
    __shared__ bf16 A_lds[128 * 32];
    __shared__ bf16 B_lds[128 * 32];
    const int tid  = threadIdx.x;
    const int w    = tid >> 6;
    const int lane = tid & 63;
    const int l16  = lane & 15, quad = lane >> 4;
    const int wm   = w >> 1, wn = w & 1;
    const int row0 = blockIdx.y * 128;
    const int col0 = blockIdx.x * 128;

    f32x4 acc[4][4] = {};

    for (int kt = 0; kt < 1024; kt += 32) {
        __syncthreads();
        {
            const bf16* ga = A + (size_t)(row0 + w * 32) * 1024 + kt;
            stage16rows(ga,             &A_lds[(w * 32) * 32], lane);
            stage16rows(ga + 16 * 1024, &A_lds[(w * 32 + 16) * 32], lane);
            const bf16* gb = B + (size_t)(col0 + w * 32) * 1024 + kt;
            stage16rows(gb,             &B_lds[(w * 32) * 32], lane);
            stage16rows(gb + 16 * 1024, &B_lds[(w * 32 + 16) * 32], lane);
        }
        __syncthreads();

        bf16x8 af[4], bf[4];
#pragma unroll
        for (int mt = 0; mt < 4; mt++) {
            const int row = wm * 64 + mt * 16 + l16;
            af[mt] = *(const bf16x8*)&A_lds[row * 32 + ((quad ^ (row & 3)) * 8)];
        }
#pragma unroll
        for (int nt = 0; nt < 4; nt++) {
            const int row = wn * 64 + nt * 16 + l16;
            bf[nt] = *(const bf16x8*)&B_lds[row * 32 + ((quad ^ (row & 3)) * 8)];
        }
#pragma unroll
        for (int mt = 0; mt < 4; mt++)
#pragma unroll
            for (int nt = 0; nt < 4; nt++)
                acc[mt][nt] = __builtin_amdgcn_mfma_f32_16x16x32_bf16(af[mt], bf[nt], acc[mt][nt], 0, 0, 0);
    }

#pragma unroll
    for (int mt = 0; mt < 4; mt++) {
        const int rbase = row0 + wm * 64 + mt * 16 + quad * 4;
#pragma unroll
        for (int nt = 0; nt < 4; nt++) {
            const int c = col0 + wn * 64 + nt * 16 + l16;
            const float bias = bias_f[c];
#pragma unroll
            for (int rg = 0; rg < 4; rg++)
                stf(out + (size_t)(rbase + rg) * 1024 + c, acc[mt][nt][rg] + bias);
        }
    }
}

// ---------------------------------------------------------------------------
extern "C" void kernel_launch(void* const* d_in, const int* in_sizes, int n_in,
                              void* d_out, int out_size, void* d_ws, size_t ws_size,
                              hipStream_t stream)
{
    const size_t SEG = (size_t)8 * 16 * 1024 * 64;   // 8388608 elems
    bf16* qn  = (bf16*)d_ws;
    bf16* kn  = qn + SEG;
    bf16* vt  = kn + SEG;
    bf16* ow  = vt + SEG;
    bf16* xb  = ow + SEG;                  // bf16 copy of x (8192x1024)
    bf16* wb  = xb + SEG;                  // bf16 copy of in_proj_weight (3072x1024)
    bf16* owb = wb + 3145728;              // bf16 copy of out_w (1024x1024)
    float* smallf = (float*)(owb + 1048576);   // 4128 floats
    int*   flag   = (int*)(smallf + 4128);

    detect_kernel<<<1, 256, 0, stream>>>((const unsigned short*)d_in[0], flag);

    convert_small_kernel<bf16><<<1, 256, 0, stream>>>(flag, 0,
        (const bf16*)d_in[2], (const bf16*)d_in[6], (const bf16*)d_in[3], (const bf16*)d_in[4], smallf);
    convert_small_kernel<float><<<1, 256, 0, stream>>>(flag, 1,
        (const float*)d_in[2], (const float*)d_in[6], (const float*)d_in[3], (const float*)d_in[4], smallf);

    convert_inputs_kernel<bf16><<<4096, 256, 0, stream>>>(flag, 0,
        (const bf16*)d_in[0], (const bf16*)d_in[1], (const bf16*)d_in[5], xb, wb, owb);
    convert_inputs_kernel<float><<<4096, 256, 0, stream>>>(flag, 1,
        (const float*)d_in[0], (const float*)d_in[1], (const float*)d_in[5], xb, wb, owb);

    // 1) qkv projection (MFMA): 8192x3072x1024
    qkv_gemm_mfma_kernel<<<dim3(3072 / 128, 8192 / 128), 256, 0, stream>>>(
        xb, wb, smallf, qn, kn, vt);

    // 2) L2-normalize q and k rows
    normalize_kernel<<<dim3((2 * 8 * 16 * 1024) / 4), 256, 0, stream>>>(qn);

    // 3) flash attention (MFMA)
    attn_mfma_kernel<<<dim3(128 * 16), 256, 0, stream>>>(qn, kn, vt, smallf, ow);

    // 4) out projection (MFMA): 8192x1024x1024
    const dim3 out_grid(1024 / 128, 8192 / 128);
    out_gemm_mfma_kernel<bf16><<<out_grid, 256, 0, stream>>>(flag, 0,
        ow, owb, smallf + 3072, (bf16*)d_out);
    out_gemm_mfma_kernel<float><<<out_grid, 256, 0, stream>>>(flag, 1,
        ow, owb, smallf + 3072, (float*)d_out);
}

// Round 6
// 301.926 us; speedup vs baseline: 13.5658x; 1.2506x over previous
//
#include <hip/hip_runtime.h>
#include <hip/hip_bf16.h>

typedef __hip_bfloat16 bf16;
typedef __attribute__((ext_vector_type(8))) short bf16x8;
typedef __attribute__((ext_vector_type(4))) float f32x4;

// Problem constants: x (L=1024, N=8, C=1024), H=16 heads, hd=64
#define LOGIT_MAX 4.6051702f   // log(1/0.01)

__device__ __forceinline__ float bflo(unsigned u) {
    union { unsigned x; float f; } c; c.x = u << 16; return c.f;
}
__device__ __forceinline__ float bfhi(unsigned u) {
    union { unsigned x; float f; } c; c.x = u & 0xffff0000u; return c.f;
}

__device__ __forceinline__ float ldf(const float* p) { return *p; }
__device__ __forceinline__ float ldf(const bf16*  p) { return __bfloat162float(*p); }

__device__ __forceinline__ float4 load4(const float* p) { return *(const float4*)p; }
__device__ __forceinline__ float4 load4(const bf16* p) {
    const uint2 u = *(const uint2*)p;
    return make_float4(bflo(u.x), bfhi(u.x), bflo(u.y), bfhi(u.y));
}

__device__ __forceinline__ void stf(float* p, float v) { *p = v; }
__device__ __forceinline__ void stf(bf16*  p, float v) { *p = __float2bfloat16(v); }

__device__ __forceinline__ void store4bf(bf16* p, float4 v) {
    union { bf16 b[4]; uint2 u; } t;
    t.b[0] = __float2bfloat16(v.x); t.b[1] = __float2bfloat16(v.y);
    t.b[2] = __float2bfloat16(v.z); t.b[3] = __float2bfloat16(v.w);
    *(uint2*)p = t.u;
}

// async global->LDS, 16B/lane; lds base wave-uniform, lane i -> base + i*16B
__device__ __forceinline__ void async16(const bf16* g, const bf16* lds) {
    __builtin_amdgcn_global_load_lds(
        (const __attribute__((address_space(1))) void*)g,
        (__attribute__((address_space(3))) void*)lds, 16, 0, 0);
}

// Stage 16 rows x 32 elems of a K-contiguous (stride 1024) matrix with XOR
// chunk swizzle: physical chunk c at row r holds global chunk c^(r&3).
__device__ __forceinline__ void stage16rows(const bf16* __restrict__ g, const bf16* lds, int lane) {
    const int r  = lane >> 2, c = lane & 3;
    const int cg = c ^ (r & 3);
    async16(g + r * 1024 + cg * 8, lds);
}

// ---------------------------------------------------------------------------
// Kernel 0: dtype detection (1 = fp32 inputs, 0 = bf16 inputs).
// ---------------------------------------------------------------------------
__global__ void detect_kernel(const unsigned short* __restrict__ x, int* __restrict__ flag)
{
    __shared__ int cnt;
    if (threadIdx.x == 0) cnt = 0;
    __syncthreads();
    int c = 0;
    for (int i = threadIdx.x; i < 4096; i += 256) {
        const unsigned e = (x[i] >> 7) & 0xFF;
        if (e >= 0x90) c++;
    }
    atomicAdd(&cnt, c);
    __syncthreads();
    if (threadIdx.x == 0) *flag = (cnt > 64) ? 1 : 0;
}

// ---------------------------------------------------------------------------
// Kernel 0b: small conversions -> fp32 ws: [0,3072) in_proj_bias,
// [3072,4096) out_b, [4096,4112) exp(min(ls,MAX)), [4112,4128) head_scale.
// ---------------------------------------------------------------------------
template <typename T>
__global__ void convert_small_kernel(const int* __restrict__ flag, int mode,
                                     const T* __restrict__ b_in, const T* __restrict__ out_b,
                                     const T* __restrict__ ls, const T* __restrict__ hs,
                                     float* __restrict__ dst)
{
    if (*flag != mode) return;
    for (int idx = threadIdx.x; idx < 4128; idx += 256) {
        float v;
        if (idx < 3072)      v = ldf(b_in + idx);
        else if (idx < 4096) v = ldf(out_b + (idx - 3072));
        else if (idx < 4112) v = expf(fminf(ldf(ls + (idx - 4096)), LOGIT_MAX));
        else                 v = ldf(hs + (idx - 4112));
        dst[idx] = v;
    }
}

// ---------------------------------------------------------------------------
// Kernel 0c: fp32 -> bf16 ws copies of x / in_proj_weight / out_w (fp32 mode
// only; in bf16 mode the GEMMs read d_in directly).
// ---------------------------------------------------------------------------
__global__ __launch_bounds__(256) void convert_inputs_kernel(
    const int* __restrict__ flag,
    const float* __restrict__ x, const float* __restrict__ w_in, const float* __restrict__ out_w,
    bf16* __restrict__ xb, bf16* __restrict__ wb, bf16* __restrict__ owb)
{
    if (*flag != 1) return;
    const size_t NX = 8388608, NW = 3145728, NO = 1048576;
    const size_t t0   = ((size_t)blockIdx.x * 256 + threadIdx.x) * 4;
    const size_t step = (size_t)gridDim.x * 256 * 4;
    for (size_t i = t0; i < NX; i += step) store4bf(xb + i, load4(x + i));
    for (size_t i = t0; i < NW; i += step) store4bf(wb + i, load4(w_in + i));
    for (size_t i = t0; i < NO; i += step) store4bf(owb + i, load4(out_w + i));
}

// ---------------------------------------------------------------------------
// Kernel 1: MFMA QKV projection with FUSED L2-normalize of q,k.
// C[8192x3072] = X . W^T; 128x128 tile, BK=32, 4 waves 2x2.
// Each wave's 64 cols = exactly one (part, head): full d=0..63 per row, so
// row norms reduce across the 16 l16 lanes (4 shuffles, once per row).
// q,k -> normalized (N*H, L, 64); v -> transposed (N*H, 64, L).
// ---------------------------------------------------------------------------
__global__ __launch_bounds__(256) void qkv_gemm_mfma_kernel(
    const int* __restrict__ flag,
    const bf16* __restrict__ Xws, const bf16* __restrict__ Wws,
    const bf16* __restrict__ Xdir, const bf16* __restrict__ Wdir,
    const float* __restrict__ bias_f,
    bf16* __restrict__ q, bf16* __restrict__ k, bf16* __restrict__ vt)
{
    const bf16* X = (*flag) ? Xws : Xdir;
    const bf16* W = (*flag) ? Wws : Wdir;
    __shared__ bf16 A_lds[128 * 32];
    __shared__ bf16 B_lds[128 * 32];
    const int tid  = threadIdx.x;
    const int w    = tid >> 6;
    const int lane = tid & 63;
    const int l16  = lane & 15, quad = lane >> 4;
    const int wm   = w >> 1, wn = w & 1;
    const int row0 = blockIdx.y * 128;
    const int col0 = blockIdx.x * 128;

    f32x4 acc[4][4] = {};

    for (int kt = 0; kt < 1024; kt += 32) {
        __syncthreads();
        {
            const bf16* ga = X + (size_t)(row0 + w * 32) * 1024 + kt;
            stage16rows(ga,             &A_lds[(w * 32) * 32], lane);
            stage16rows(ga + 16 * 1024, &A_lds[(w * 32 + 16) * 32], lane);
            const bf16* gb = W + (size_t)(col0 + w * 32) * 1024 + kt;
            stage16rows(gb,             &B_lds[(w * 32) * 32], lane);
            stage16rows(gb + 16 * 1024, &B_lds[(w * 32 + 16) * 32], lane);
        }
        __syncthreads();

        bf16x8 af[4], bf[4];
#pragma unroll
        for (int mt = 0; mt < 4; mt++) {
            const int row = wm * 64 + mt * 16 + l16;
            af[mt] = *(const bf16x8*)&A_lds[row * 32 + ((quad ^ (row & 3)) * 8)];
        }
#pragma unroll
        for (int nt = 0; nt < 4; nt++) {
            const int row = wn * 64 + nt * 16 + l16;
            bf[nt] = *(const bf16x8*)&B_lds[row * 32 + ((quad ^ (row & 3)) * 8)];
        }
#pragma unroll
        for (int mt = 0; mt < 4; mt++)
#pragma unroll
            for (int nt = 0; nt < 4; nt++)
                acc[mt][nt] = __builtin_amdgcn_mfma_f32_16x16x32_bf16(af[mt], bf[nt], acc[mt][nt], 0, 0, 0);
    }

    const int cbase = col0 + wn * 64;          // wave-uniform
    const int part  = cbase >> 10;
    const int h     = (cbase & 1023) >> 6;
    float bias[4];
#pragma unroll
    for (int nt = 0; nt < 4; nt++) bias[nt] = bias_f[cbase + nt * 16 + l16];

    if (part < 2) {
        bf16* dst0 = (part == 0) ? q : k;
#pragma unroll
        for (int mt = 0; mt < 4; mt++) {
#pragma unroll
            for (int rg = 0; rg < 4; rg++) {
                const int r = row0 + wm * 64 + mt * 16 + quad * 4 + rg;
                const int l = r >> 3, nn = r & 7;
                float val[4]; float ss = 0.f;
#pragma unroll
                for (int nt = 0; nt < 4; nt++) {
                    val[nt] = acc[mt][nt][rg] + bias[nt];
                    ss += val[nt] * val[nt];
                }
                ss += __shfl_xor(ss, 1); ss += __shfl_xor(ss, 2);
                ss += __shfl_xor(ss, 4); ss += __shfl_xor(ss, 8);
                const float inv = 1.f / fmaxf(sqrtf(ss), 1e-12f);
                bf16* dp = dst0 + ((size_t)((nn * 16 + h) * 1024 + l)) * 64;
#pragma unroll
                for (int nt = 0; nt < 4; nt++)
                    dp[nt * 16 + l16] = __float2bfloat16(val[nt] * inv);
            }
        }
    } else {
#pragma unroll
        for (int mt = 0; mt < 4; mt++) {
#pragma unroll
            for (int rg = 0; rg < 4; rg++) {
                const int r = row0 + wm * 64 + mt * 16 + quad * 4 + rg;
                const int l = r >> 3, nn = r & 7;
#pragma unroll
                for (int nt = 0; nt < 4; nt++) {
                    const int d = nt * 16 + l16;
                    vt[((size_t)((nn * 16 + h) * 64 + d)) * 1024 + l] =
                        __float2bfloat16(acc[mt][nt][rg] + bias[nt]);
                }
            }
        }
    }
}

// ---------------------------------------------------------------------------
// Kernel 3: MFMA flash attention v2.
// Block = 4 waves x 32 qrows = 128 qrows of one (n,h); 16 key-tiles of 64.
// S^T via mfma(A=K, B=Q): lane holds qrow=l16, keys quad*4+r per subtile ->
// P written as 4 packed b64/subtile-pair. Fixed-max softmax (max = ls, since
// cosine scores <= ls): no online max/rescale, per-lane partial sums, one
// cross-lane reduction at the end. K/V staged via global_load_lds with XOR
// chunk swizzle (phys chunk c holds logical c^(row&7)).
// ---------------------------------------------------------------------------
__global__ __launch_bounds__(256, 4) void attn_mfma_kernel(
    const bf16* __restrict__ q, const bf16* __restrict__ k,
    const bf16* __restrict__ vt, const float* __restrict__ scale_f,
    bf16* __restrict__ o)
{
    __shared__ bf16 K_lds[64][64];     // [key][d], swizzled chunks
    __shared__ bf16 Vt_lds[64][64];    // [d][key], swizzled chunks
    __shared__ bf16 P_lds[4][32][72];  // wave-private [qrow][key]
    __shared__ float l_lds[4][32];

    const int bid  = blockIdx.x;
    const int qt   = bid & 7;          // 8 q-tiles of 128 rows
    const int nh   = bid >> 3;         // 0..127
    const int h    = nh & 15;
    const int n    = nh >> 4;
    const int tid  = threadIdx.x;
    const int w    = tid >> 6;
    const int lane = tid & 63;
    const int l16  = lane & 15;
    const int quad = lane >> 4;

    const size_t base = (size_t)nh * (1024 * 64);
    const float ls   = scale_f[4096 + h];
    const float hs   = scale_f[4112 + h];
    const float lsl2 = ls * 1.4426950408889634f;

    // Q B-frags (persist): qrows qt*128 + w*32 + u*16 + l16
    bf16x8 qf[2][2];
#pragma unroll
    for (int u = 0; u < 2; u++) {
        const int qrow = qt * 128 + w * 32 + u * 16 + l16;
        const bf16* qp = q + base + (size_t)qrow * 64 + quad * 8;
        qf[u][0] = *(const bf16x8*)qp;
        qf[u][1] = *(const bf16x8*)(qp + 32);
    }

    f32x4 o_acc[2][4] = {};
    float l_part[2] = {0.f, 0.f};

    const int sr = lane >> 3;          // 0..7 (row within 8-row staging inst)
    const int sc = lane & 7;           // phys chunk

    for (int j0 = 0; j0 < 1024; j0 += 64) {
        __syncthreads();
#pragma unroll
        for (int half = 0; half < 2; half++) {
            const int br  = w * 16 + half * 8;
            const int row = br + sr;
            const int cg  = sc ^ (row & 7);
            async16(k  + base + (size_t)(j0 + row) * 64 + cg * 8, &K_lds[br][0]);
            async16(vt + base + (size_t)row * 1024 + j0 + cg * 8, &Vt_lds[br][0]);
        }
        __syncthreads();

        // S^T = K . Q^T : per key-subtile s, rows(m)=keys s*16+l16
        f32x4 s8[2][4];
#pragma unroll
        for (int s = 0; s < 4; s++) {
            const int krow = s * 16 + l16;
            const int swz  = krow & 7;
            const bf16x8 kf0 = *(const bf16x8*)&K_lds[krow][(quad ^ swz) * 8];
            const bf16x8 kf1 = *(const bf16x8*)&K_lds[krow][((quad + 4) ^ swz) * 8];
#pragma unroll
            for (int u = 0; u < 2; u++) {
                f32x4 a = {};
                a = __builtin_amdgcn_mfma_f32_16x16x32_bf16(kf0, qf[u][0], a, 0, 0, 0);
                a = __builtin_amdgcn_mfma_f32_16x16x32_bf16(kf1, qf[u][1], a, 0, 0, 0);
                s8[u][s] = a;
            }
        }

        // p = exp(ls*(s-1)) = exp2(lsl2*s - lsl2); pack 4 keys -> b64 store
#pragma unroll
        for (int u = 0; u < 2; u++) {
#pragma unroll
            for (int s = 0; s < 4; s++) {
                union { bf16 b[4]; uint2 uu; } pk;
                float sum = 0.f;
#pragma unroll
                for (int r = 0; r < 4; r++) {
                    const float p = exp2f(fmaf(s8[u][s][r], lsl2, -lsl2));
                    pk.b[r] = __float2bfloat16(p);
                    sum += p;
                }
                l_part[u] += sum;
                *(uint2*)&P_lds[w][u * 16 + l16][s * 16 + quad * 4] = pk.uu;
            }
        }

        // PV: A = P (m=qrow, k=key), B = Vt (n=d, k=key)
        bf16x8 pf[2][2];
#pragma unroll
        for (int u = 0; u < 2; u++) {
            pf[u][0] = *(const bf16x8*)&P_lds[w][u * 16 + l16][quad * 8];
            pf[u][1] = *(const bf16x8*)&P_lds[w][u * 16 + l16][32 + quad * 8];
        }
#pragma unroll
        for (int ds = 0; ds < 4; ds++) {
            const int vrow = ds * 16 + l16;
            const int swz  = vrow & 7;
            const bf16x8 vf0 = *(const bf16x8*)&Vt_lds[vrow][(quad ^ swz) * 8];
            const bf16x8 vf1 = *(const bf16x8*)&Vt_lds[vrow][((quad + 4) ^ swz) * 8];
#pragma unroll
            for (int u = 0; u < 2; u++) {
                o_acc[u][ds] = __builtin_amdgcn_mfma_f32_16x16x32_bf16(pf[u][0], vf0, o_acc[u][ds], 0, 0, 0);
                o_acc[u][ds] = __builtin_amdgcn_mfma_f32_16x16x32_bf16(pf[u][1], vf1, o_acc[u][ds], 0, 0, 0);
            }
        }
    }

    // final l reduction (lanes sharing l16 across quads hold partials)
#pragma unroll
    for (int u = 0; u < 2; u++) {
        float v = l_part[u];
        v += __shfl_xor(v, 16);
        v += __shfl_xor(v, 32);
        l_lds[w][u * 16 + l16] = v;
    }

    // epilogue: o_acc rows = quad*4+r (qrow-sub), col = l16 (d-sub)
#pragma unroll
    for (int u = 0; u < 2; u++) {
#pragma unroll
        for (int r = 0; r < 4; r++) {
            const float inv = hs / l_lds[w][u * 16 + quad * 4 + r];
            const int row_l = qt * 128 + w * 32 + u * 16 + quad * 4 + r;
            bf16* dst = o + ((size_t)row_l * 8 + n) * 1024 + h * 64 + l16;
#pragma unroll
            for (int ds = 0; ds < 4; ds++)
                dst[ds * 16] = __float2bfloat16(o_acc[u][ds][r] * inv);
        }
    }
}

// ---------------------------------------------------------------------------
// Kernel 4: MFMA out projection. out[8192x1024] = A . W^T + b.
// ---------------------------------------------------------------------------
template <typename TOUT>
__global__ __launch_bounds__(256) void out_gemm_mfma_kernel(
    const int* __restrict__ flag, int mode,
    const bf16* __restrict__ A, const bf16* __restrict__ B,
    const float* __restrict__ bias_f, TOUT* __restrict__ out)
{
    if (*flag != mode) return;
    __shared__ bf16 A_lds[128 * 32];
    __shared__ bf16 B_lds[128 * 32];
    const int tid  = threadIdx.x;
    const int w    = tid >> 6;
    const int lane = tid & 63;
    const int l16  = lane & 15, quad = lane >> 4;
    const int wm   = w >> 1, wn = w & 1;
    const int row0 = blockIdx.y * 128;
    const int col0 = blockIdx.x * 128;

    f32x4 acc[4][4] = {};

    for (int kt = 0; kt < 1024; kt += 32) {
        __syncthreads();
        {
            const bf16* ga = A + (size_t)(row0 + w * 32) * 1024 + kt;
            stage16rows(ga,             &A_lds[(w * 32) * 32], lane);
            stage16rows(ga + 16 * 1024, &A_lds[(w * 32 + 16) * 32], lane);
            const bf16* gb = B + (size_t)(col0 + w * 32) * 1024 + kt;
            stage16rows(gb,             &B_lds[(w * 32) * 32], lane);
            stage16rows(gb + 16 * 1024, &B_lds[(w * 32 + 16) * 32], lane);
        }
        __syncthreads();

        bf16x8 af[4], bf[4];
#pragma unroll
        for (int mt = 0; mt < 4; mt++) {
            const int row = wm * 64 + mt * 16 + l16;
            af[mt] = *(const bf16x8*)&A_lds[row * 32 + ((quad ^ (row & 3)) * 8)];
        }
#pragma unroll
        for (int nt = 0; nt < 4; nt++) {
            const int row = wn * 64 + nt * 16 + l16;
            bf[nt] = *(const bf16x8*)&B_lds[row * 32 + ((quad ^ (row & 3)) * 8)];
        }
#pragma unroll
        for (int mt = 0; mt < 4; mt++)
#pragma unroll
            for (int nt = 0; nt < 4; nt++)
                acc[mt][nt] = __builtin_amdgcn_mfma_f32_16x16x32_bf16(af[mt], bf[nt], acc[mt][nt], 0, 0, 0);
    }

#pragma unroll
    for (int mt = 0; mt < 4; mt++) {
        const int rbase = row0 + wm * 64 + mt * 16 + quad * 4;
#pragma unroll
        for (int nt = 0; nt < 4; nt++) {
            const int c = col0 + wn * 64 + nt * 16 + l16;
            const float bias = bias_f[c];
#pragma unroll
            for (int rg = 0; rg < 4; rg++)
                stf(out + (size_t)(rbase + rg) * 1024 + c, acc[mt][nt][rg] + bias);
        }
    }
}

// ---------------------------------------------------------------------------
extern "C" void kernel_launch(void* const* d_in, const int* in_sizes, int n_in,
                              void* d_out, int out_size, void* d_ws, size_t ws_size,
                              hipStream_t stream)
{
    const size_t SEG = (size_t)8 * 16 * 1024 * 64;   // 8388608 elems
    bf16* qn  = (bf16*)d_ws;
    bf16* kn  = qn + SEG;
    bf16* vt  = kn + SEG;
    bf16* ow  = vt + SEG;
    bf16* xb  = ow + SEG;                  // bf16 copy of x (fp32 mode)
    bf16* wb  = xb + SEG;                  // bf16 copy of in_proj_weight
    bf16* owb = wb + 3145728;              // bf16 copy of out_w
    float* smallf = (float*)(owb + 1048576);   // 4128 floats
    int*   flag   = (int*)(smallf + 4128);

    detect_kernel<<<1, 256, 0, stream>>>((const unsigned short*)d_in[0], flag);

    convert_small_kernel<bf16><<<1, 256, 0, stream>>>(flag, 0,
        (const bf16*)d_in[2], (const bf16*)d_in[6], (const bf16*)d_in[3], (const bf16*)d_in[4], smallf);
    convert_small_kernel<float><<<1, 256, 0, stream>>>(flag, 1,
        (const float*)d_in[2], (const float*)d_in[6], (const float*)d_in[3], (const float*)d_in[4], smallf);

    convert_inputs_kernel<<<4096, 256, 0, stream>>>(flag,
        (const float*)d_in[0], (const float*)d_in[1], (const float*)d_in[5], xb, wb, owb);

    // 1) qkv projection (MFMA) + fused q/k L2-normalize
    qkv_gemm_mfma_kernel<<<dim3(3072 / 128, 8192 / 128), 256, 0, stream>>>(
        flag, xb, wb, (const bf16*)d_in[0], (const bf16*)d_in[1], smallf, qn, kn, vt);

    // 2) flash attention v2 (MFMA, fixed-max softmax)
    attn_mfma_kernel<<<dim3(128 * 8), 256, 0, stream>>>(qn, kn, vt, smallf, ow);

    // 3) out projection (MFMA): W pointer picked per mode at launch
    const dim3 out_grid(1024 / 128, 8192 / 128);
    out_gemm_mfma_kernel<bf16><<<out_grid, 256, 0, stream>>>(flag, 0,
        ow, (const bf16*)d_in[5], smallf + 3072, (bf16*)d_out);
    out_gemm_mfma_kernel<float><<<out_grid, 256, 0, stream>>>(flag, 1,
        ow, owb, smallf + 3072, (float*)d_out);
}

// Round 7
// 288.105 us; speedup vs baseline: 14.2166x; 1.0480x over previous
//
#include <hip/hip_runtime.h>
#include <hip/hip_bf16.h>

typedef __hip_bfloat16 bf16;
typedef __attribute__((ext_vector_type(8))) short bf16x8;
typedef __attribute__((ext_vector_type(4))) float f32x4;

// Problem constants: x (L=1024, N=8, C=1024), H=16 heads, hd=64
#define LOGIT_MAX 4.6051702f   // log(1/0.01)

__device__ __forceinline__ float bflo(unsigned u) {
    union { unsigned x; float f; } c; c.x = u << 16; return c.f;
}
__device__ __forceinline__ float bfhi(unsigned u) {
    union { unsigned x; float f; } c; c.x = u & 0xffff0000u; return c.f;
}

__device__ __forceinline__ float4 load4(const float* p) { return *(const float4*)p; }

__device__ __forceinline__ void stf(float* p, float v) { *p = v; }
__device__ __forceinline__ void stf(bf16*  p, float v) { *p = __float2bfloat16(v); }

__device__ __forceinline__ void store4bf(bf16* p, float4 v) {
    union { bf16 b[4]; uint2 u; } t;
    t.b[0] = __float2bfloat16(v.x); t.b[1] = __float2bfloat16(v.y);
    t.b[2] = __float2bfloat16(v.z); t.b[3] = __float2bfloat16(v.w);
    *(uint2*)p = t.u;
}

// async global->LDS, 16B/lane; lds base wave-uniform, lane i -> base + i*16B
__device__ __forceinline__ void async16(const bf16* g, const bf16* lds) {
    __builtin_amdgcn_global_load_lds(
        (const __attribute__((address_space(1))) void*)g,
        (__attribute__((address_space(3))) void*)lds, 16, 0, 0);
}

// ---------------------------------------------------------------------------
// Kernel 0: dtype detection (1 = fp32 inputs, 0 = bf16 inputs).
// ---------------------------------------------------------------------------
__global__ void detect_kernel(const unsigned short* __restrict__ x, int* __restrict__ flag)
{
    __shared__ int cnt;
    if (threadIdx.x == 0) cnt = 0;
    __syncthreads();
    int c = 0;
    for (int i = threadIdx.x; i < 4096; i += 256) {
        const unsigned e = (x[i] >> 7) & 0xFF;
        if (e >= 0x90) c++;
    }
    atomicAdd(&cnt, c);
    __syncthreads();
    if (threadIdx.x == 0) *flag = (cnt > 64) ? 1 : 0;
}

// ---------------------------------------------------------------------------
// Kernel 0b (merged prep): small conversions -> fp32 ws (block 0), and in
// fp32 mode bf16 ws copies of x / in_proj_weight / out_w (all blocks).
// smallf: [0,3072) in_proj_bias, [3072,4096) out_b,
//         [4096,4112) exp(min(ls,MAX)), [4112,4128) head_scale.
// ---------------------------------------------------------------------------
__global__ __launch_bounds__(256) void prep_kernel(
    const int* __restrict__ flag,
    const void* __restrict__ x, const void* __restrict__ w_in, const void* __restrict__ out_w,
    const void* __restrict__ b_in, const void* __restrict__ out_b,
    const void* __restrict__ ls, const void* __restrict__ hs,
    bf16* __restrict__ xb, bf16* __restrict__ wb, bf16* __restrict__ owb,
    float* __restrict__ smallf)
{
    const int f = *flag;
    if (blockIdx.x == 0) {
        for (int idx = threadIdx.x; idx < 4128; idx += 256) {
            float v;
            if (f) {
                if (idx < 3072)      v = ((const float*)b_in)[idx];
                else if (idx < 4096) v = ((const float*)out_b)[idx - 3072];
                else if (idx < 4112) v = expf(fminf(((const float*)ls)[idx - 4096], LOGIT_MAX));
                else                 v = ((const float*)hs)[idx - 4112];
            } else {
                if (idx < 3072)      v = __bfloat162float(((const bf16*)b_in)[idx]);
                else if (idx < 4096) v = __bfloat162float(((const bf16*)out_b)[idx - 3072]);
                else if (idx < 4112) v = expf(fminf(__bfloat162float(((const bf16*)ls)[idx - 4096]), LOGIT_MAX));
                else                 v = __bfloat162float(((const bf16*)hs)[idx - 4112]);
            }
            smallf[idx] = v;
        }
    }
    if (f != 1) return;
    const size_t NX = 8388608, NW = 3145728, NO = 1048576;
    const size_t t0   = ((size_t)blockIdx.x * 256 + threadIdx.x) * 4;
    const size_t step = (size_t)gridDim.x * 256 * 4;
    for (size_t i = t0; i < NX; i += step) store4bf(xb + i, load4((const float*)x + i));
    for (size_t i = t0; i < NW; i += step) store4bf(wb + i, load4((const float*)w_in + i));
    for (size_t i = t0; i < NO; i += step) store4bf(owb + i, load4((const float*)out_w + i));
}

// ---------------------------------------------------------------------------
// Kernel 1: MFMA QKV projection, BK=64 (32 MFMA per barrier pair), fused
// q/k L2-normalize. C[8192x3072] = X . W^T; 128x128 tile, 4 waves 2x2.
// LDS rows of 64 elems, 8 chunks of 8, XOR swizzle phys c = logical c^(row&7).
// q,k -> normalized (N*H, L, 64); v -> transposed (N*H, 64, L).
// ---------------------------------------------------------------------------
__global__ __launch_bounds__(256) void qkv_gemm_mfma_kernel(
    const int* __restrict__ flag,
    const bf16* __restrict__ Xws, const bf16* __restrict__ Wws,
    const bf16* __restrict__ Xdir, const bf16* __restrict__ Wdir,
    const float* __restrict__ bias_f,
    bf16* __restrict__ q, bf16* __restrict__ k, bf16* __restrict__ vt)
{
    const bf16* X = (*flag) ? Xws : Xdir;
    const bf16* W = (*flag) ? Wws : Wdir;
    __shared__ bf16 A_lds[128 * 64];
    __shared__ bf16 B_lds[128 * 64];
    const int tid  = threadIdx.x;
    const int w    = tid >> 6;
    const int lane = tid & 63;
    const int l16  = lane & 15, quad = lane >> 4;
    const int wm   = w >> 1, wn = w & 1;
    const int row0 = blockIdx.y * 128;
    const int col0 = blockIdx.x * 128;
    const int sr   = lane >> 3, sc = lane & 7;
    const int scg  = sc ^ sr;            // source chunk for swizzled staging

    f32x4 acc[4][4] = {};

    for (int kt = 0; kt < 1024; kt += 64) {
        __syncthreads();
#pragma unroll
        for (int i = 0; i < 4; i++) {
            const int br = w * 32 + i * 8;     // 8 rows per inst, br % 8 == 0
            async16(X + (size_t)(row0 + br + sr) * 1024 + kt + scg * 8, &A_lds[br * 64]);
            async16(W + (size_t)(col0 + br + sr) * 1024 + kt + scg * 8, &B_lds[br * 64]);
        }
        __syncthreads();

#pragma unroll
        for (int kh = 0; kh < 2; kh++) {
            bf16x8 af[4], bf[4];
#pragma unroll
            for (int mt = 0; mt < 4; mt++) {
                const int row = wm * 64 + mt * 16 + l16;
                af[mt] = *(const bf16x8*)&A_lds[row * 64 + (((quad + kh * 4) ^ (row & 7)) * 8)];
            }
#pragma unroll
            for (int nt = 0; nt < 4; nt++) {
                const int row = wn * 64 + nt * 16 + l16;
                bf[nt] = *(const bf16x8*)&B_lds[row * 64 + (((quad + kh * 4) ^ (row & 7)) * 8)];
            }
#pragma unroll
            for (int mt = 0; mt < 4; mt++)
#pragma unroll
                for (int nt = 0; nt < 4; nt++)
                    acc[mt][nt] = __builtin_amdgcn_mfma_f32_16x16x32_bf16(af[mt], bf[nt], acc[mt][nt], 0, 0, 0);
        }
    }

    const int cbase = col0 + wn * 64;          // wave-uniform
    const int part  = cbase >> 10;
    const int h     = (cbase & 1023) >> 6;
    float bias[4];
#pragma unroll
    for (int nt = 0; nt < 4; nt++) bias[nt] = bias_f[cbase + nt * 16 + l16];

    if (part < 2) {
        bf16* dst0 = (part == 0) ? q : k;
#pragma unroll
        for (int mt = 0; mt < 4; mt++) {
#pragma unroll
            for (int rg = 0; rg < 4; rg++) {
                const int r = row0 + wm * 64 + mt * 16 + quad * 4 + rg;
                const int l = r >> 3, nn = r & 7;
                float val[4]; float ss = 0.f;
#pragma unroll
                for (int nt = 0; nt < 4; nt++) {
                    val[nt] = acc[mt][nt][rg] + bias[nt];
                    ss += val[nt] * val[nt];
                }
                ss += __shfl_xor(ss, 1); ss += __shfl_xor(ss, 2);
                ss += __shfl_xor(ss, 4); ss += __shfl_xor(ss, 8);
                const float inv = 1.f / fmaxf(sqrtf(ss), 1e-12f);
                bf16* dp = dst0 + ((size_t)((nn * 16 + h) * 1024 + l)) * 64;
#pragma unroll
                for (int nt = 0; nt < 4; nt++)
                    dp[nt * 16 + l16] = __float2bfloat16(val[nt] * inv);
            }
        }
    } else {
#pragma unroll
        for (int mt = 0; mt < 4; mt++) {
#pragma unroll
            for (int rg = 0; rg < 4; rg++) {
                const int r = row0 + wm * 64 + mt * 16 + quad * 4 + rg;
                const int l = r >> 3, nn = r & 7;
#pragma unroll
                for (int nt = 0; nt < 4; nt++) {
                    const int d = nt * 16 + l16;
                    vt[((size_t)((nn * 16 + h) * 64 + d)) * 1024 + l] =
                        __float2bfloat16(acc[mt][nt][rg] + bias[nt]);
                }
            }
        }
    }
}

// ---------------------------------------------------------------------------
// Kernel 3: MFMA flash attention v2 (unchanged from R6).
// ---------------------------------------------------------------------------
__global__ __launch_bounds__(256, 4) void attn_mfma_kernel(
    const bf16* __restrict__ q, const bf16* __restrict__ k,
    const bf16* __restrict__ vt, const float* __restrict__ scale_f,
    bf16* __restrict__ o)
{
    __shared__ bf16 K_lds[64][64];
    __shared__ bf16 Vt_lds[64][64];
    __shared__ bf16 P_lds[4][32][72];
    __shared__ float l_lds[4][32];

    const int bid  = blockIdx.x;
    const int qt   = bid & 7;
    const int nh   = bid >> 3;
    const int h    = nh & 15;
    const int n    = nh >> 4;
    const int tid  = threadIdx.x;
    const int w    = tid >> 6;
    const int lane = tid & 63;
    const int l16  = lane & 15;
    const int quad = lane >> 4;

    const size_t base = (size_t)nh * (1024 * 64);
    const float ls   = scale_f[4096 + h];
    const float hs   = scale_f[4112 + h];
    const float lsl2 = ls * 1.4426950408889634f;

    bf16x8 qf[2][2];
#pragma unroll
    for (int u = 0; u < 2; u++) {
        const int qrow = qt * 128 + w * 32 + u * 16 + l16;
        const bf16* qp = q + base + (size_t)qrow * 64 + quad * 8;
        qf[u][0] = *(const bf16x8*)qp;
        qf[u][1] = *(const bf16x8*)(qp + 32);
    }

    f32x4 o_acc[2][4] = {};
    float l_part[2] = {0.f, 0.f};

    const int sr = lane >> 3;
    const int sc = lane & 7;

    for (int j0 = 0; j0 < 1024; j0 += 64) {
        __syncthreads();
#pragma unroll
        for (int half = 0; half < 2; half++) {
            const int br  = w * 16 + half * 8;
            const int row = br + sr;
            const int cg  = sc ^ (row & 7);
            async16(k  + base + (size_t)(j0 + row) * 64 + cg * 8, &K_lds[br][0]);
            async16(vt + base + (size_t)row * 1024 + j0 + cg * 8, &Vt_lds[br][0]);
        }
        __syncthreads();

        f32x4 s8[2][4];
#pragma unroll
        for (int s = 0; s < 4; s++) {
            const int krow = s * 16 + l16;
            const int swz  = krow & 7;
            const bf16x8 kf0 = *(const bf16x8*)&K_lds[krow][(quad ^ swz) * 8];
            const bf16x8 kf1 = *(const bf16x8*)&K_lds[krow][((quad + 4) ^ swz) * 8];
#pragma unroll
            for (int u = 0; u < 2; u++) {
                f32x4 a = {};
                a = __builtin_amdgcn_mfma_f32_16x16x32_bf16(kf0, qf[u][0], a, 0, 0, 0);
                a = __builtin_amdgcn_mfma_f32_16x16x32_bf16(kf1, qf[u][1], a, 0, 0, 0);
                s8[u][s] = a;
            }
        }

#pragma unroll
        for (int u = 0; u < 2; u++) {
#pragma unroll
            for (int s = 0; s < 4; s++) {
                union { bf16 b[4]; uint2 uu; } pk;
                float sum = 0.f;
#pragma unroll
                for (int r = 0; r < 4; r++) {
                    const float p = exp2f(fmaf(s8[u][s][r], lsl2, -lsl2));
                    pk.b[r] = __float2bfloat16(p);
                    sum += p;
                }
                l_part[u] += sum;
                *(uint2*)&P_lds[w][u * 16 + l16][s * 16 + quad * 4] = pk.uu;
            }
        }

        bf16x8 pf[2][2];
#pragma unroll
        for (int u = 0; u < 2; u++) {
            pf[u][0] = *(const bf16x8*)&P_lds[w][u * 16 + l16][quad * 8];
            pf[u][1] = *(const bf16x8*)&P_lds[w][u * 16 + l16][32 + quad * 8];
        }
#pragma unroll
        for (int ds = 0; ds < 4; ds++) {
            const int vrow = ds * 16 + l16;
            const int swz  = vrow & 7;
            const bf16x8 vf0 = *(const bf16x8*)&Vt_lds[vrow][(quad ^ swz) * 8];
            const bf16x8 vf1 = *(const bf16x8*)&Vt_lds[vrow][((quad + 4) ^ swz) * 8];
#pragma unroll
            for (int u = 0; u < 2; u++) {
                o_acc[u][ds] = __builtin_amdgcn_mfma_f32_16x16x32_bf16(pf[u][0], vf0, o_acc[u][ds], 0, 0, 0);
                o_acc[u][ds] = __builtin_amdgcn_mfma_f32_16x16x32_bf16(pf[u][1], vf1, o_acc[u][ds], 0, 0, 0);
            }
        }
    }

#pragma unroll
    for (int u = 0; u < 2; u++) {
        float v = l_part[u];
        v += __shfl_xor(v, 16);
        v += __shfl_xor(v, 32);
        l_lds[w][u * 16 + l16] = v;
    }

#pragma unroll
    for (int u = 0; u < 2; u++) {
#pragma unroll
        for (int r = 0; r < 4; r++) {
            const float inv = hs / l_lds[w][u * 16 + quad * 4 + r];
            const int row_l = qt * 128 + w * 32 + u * 16 + quad * 4 + r;
            bf16* dst = o + ((size_t)row_l * 8 + n) * 1024 + h * 64 + l16;
#pragma unroll
            for (int ds = 0; ds < 4; ds++)
                dst[ds * 16] = __float2bfloat16(o_acc[u][ds][r] * inv);
        }
    }
}

// ---------------------------------------------------------------------------
// Kernel 4: MFMA out projection, BK=64. out[8192x1024] = A . W^T + b.
// ---------------------------------------------------------------------------
template <typename TOUT>
__global__ __launch_bounds__(256) void out_gemm_mfma_kernel(
    const int* __restrict__ flag, int mode,
    const bf16* __restrict__ A, const bf16* __restrict__ B,
    const float* __restrict__ bias_f, TOUT* __restrict__ out)
{
    if (*flag != mode) return;
    __shared__ bf16 A_lds[128 * 64];
    __shared__ bf16 B_lds[128 * 64];
    const int tid  = threadIdx.x;
    const int w    = tid >> 6;
    const int lane = tid & 63;
    const int l16  = lane & 15, quad = lane >> 4;
    const int wm   = w >> 1, wn = w & 1;
    const int row0 = blockIdx.y * 128;
    const int col0 = blockIdx.x * 128;
    const int sr   = lane >> 3, sc = lane & 7;
    const int scg  = sc ^ sr;

    f32x4 acc[4][4] = {};

    for (int kt = 0; kt < 1024; kt += 64) {
        __syncthreads();
#pragma unroll
        for (int i = 0; i < 4; i++) {
            const int br = w * 32 + i * 8;
            async16(A + (size_t)(row0 + br + sr) * 1024 + kt + scg * 8, &A_lds[br * 64]);
            async16(B + (size_t)(col0 + br + sr) * 1024 + kt + scg * 8, &B_lds[br * 64]);
        }
        __syncthreads();

#pragma unroll
        for (int kh = 0; kh < 2; kh++) {
            bf16x8 af[4], bf[4];
#pragma unroll
            for (int mt = 0; mt < 4; mt++) {
                const int row = wm * 64 + mt * 16 + l16;
                af[mt] = *(const bf16x8*)&A_lds[row * 64 + (((quad + kh * 4) ^ (row & 7)) * 8)];
            }
#pragma unroll
            for (int nt = 0; nt < 4; nt++) {
                const int row = wn * 64 + nt * 16 + l16;
                bf[nt] = *(const bf16x8*)&B_lds[row * 64 + (((quad + kh * 4) ^ (row & 7)) * 8)];
            }
#pragma unroll
            for (int mt = 0; mt < 4; mt++)
#pragma unroll
                for (int nt = 0; nt < 4; nt++)
                    acc[mt][nt] = __builtin_amdgcn_mfma_f32_16x16x32_bf16(af[mt], bf[nt], acc[mt][nt], 0, 0, 0);
        }
    }

#pragma unroll
    for (int mt = 0; mt < 4; mt++) {
        const int rbase = row0 + wm * 64 + mt * 16 + quad * 4;
#pragma unroll
        for (int nt = 0; nt < 4; nt++) {
            const int c = col0 + wn * 64 + nt * 16 + l16;
            const float bias = bias_f[c];
#pragma unroll
            for (int rg = 0; rg < 4; rg++)
                stf(out + (size_t)(rbase + rg) * 1024 + c, acc[mt][nt][rg] + bias);
        }
    }
}

// ---------------------------------------------------------------------------
extern "C" void kernel_launch(void* const* d_in, const int* in_sizes, int n_in,
                              void* d_out, int out_size, void* d_ws, size_t ws_size,
                              hipStream_t stream)
{
    const size_t SEG = (size_t)8 * 16 * 1024 * 64;   // 8388608 elems
    bf16* qn  = (bf16*)d_ws;
    bf16* kn  = qn + SEG;
    bf16* vt  = kn + SEG;
    bf16* ow  = vt + SEG;
    bf16* xb  = ow + SEG;                  // bf16 copy of x (fp32 mode)
    bf16* wb  = xb + SEG;                  // bf16 copy of in_proj_weight
    bf16* owb = wb + 3145728;              // bf16 copy of out_w
    float* smallf = (float*)(owb + 1048576);   // 4128 floats
    int*   flag   = (int*)(smallf + 4128);

    detect_kernel<<<1, 256, 0, stream>>>((const unsigned short*)d_in[0], flag);

    prep_kernel<<<4096, 256, 0, stream>>>(flag,
        d_in[0], d_in[1], d_in[5], d_in[2], d_in[6], d_in[3], d_in[4],
        xb, wb, owb, smallf);

    // 1) qkv projection (MFMA, BK=64) + fused q/k L2-normalize
    qkv_gemm_mfma_kernel<<<dim3(3072 / 128, 8192 / 128), 256, 0, stream>>>(
        flag, xb, wb, (const bf16*)d_in[0], (const bf16*)d_in[1], smallf, qn, kn, vt);

    // 2) flash attention v2 (MFMA, fixed-max softmax)
    attn_mfma_kernel<<<dim3(128 * 8), 256, 0, stream>>>(qn, kn, vt, smallf, ow);

    // 3) out projection (MFMA, BK=64): W pointer picked per mode at launch
    const dim3 out_grid(1024 / 128, 8192 / 128);
    out_gemm_mfma_kernel<bf16><<<out_grid, 256, 0, stream>>>(flag, 0,
        ow, (const bf16*)d_in[5], smallf + 3072, (bf16*)d_out);
    out_gemm_mfma_kernel<float><<<out_grid, 256, 0, stream>>>(flag, 1,
        ow, owb, smallf + 3072, (float*)d_out);
}

// Round 8
// 280.200 us; speedup vs baseline: 14.6176x; 1.0282x over previous
//
#include <hip/hip_runtime.h>
#include <hip/hip_bf16.h>

typedef __hip_bfloat16 bf16;
typedef __attribute__((ext_vector_type(8))) short bf16x8;
typedef __attribute__((ext_vector_type(4))) float f32x4;

// Problem constants: x (L=1024, N=8, C=1024), H=16 heads, hd=64
#define LOGIT_MAX 4.6051702f   // log(1/0.01)

__device__ __forceinline__ float4 load4(const float* p) { return *(const float4*)p; }

__device__ __forceinline__ void stf(float* p, float v) { *p = v; }
__device__ __forceinline__ void stf(bf16*  p, float v) { *p = __float2bfloat16(v); }

__device__ __forceinline__ void store4bf(bf16* p, float4 v) {
    union { bf16 b[4]; uint2 u; } t;
    t.b[0] = __float2bfloat16(v.x); t.b[1] = __float2bfloat16(v.y);
    t.b[2] = __float2bfloat16(v.z); t.b[3] = __float2bfloat16(v.w);
    *(uint2*)p = t.u;
}

// async global->LDS, 16B/lane; lds base wave-uniform, lane i -> base + i*16B
__device__ __forceinline__ void async16(const bf16* g, const bf16* lds) {
    __builtin_amdgcn_global_load_lds(
        (const __attribute__((address_space(1))) void*)g,
        (__attribute__((address_space(3))) void*)lds, 16, 0, 0);
}

// ---------------------------------------------------------------------------
// Kernel 0: dtype detection (1 = fp32 inputs, 0 = bf16 inputs).
// ---------------------------------------------------------------------------
__global__ void detect_kernel(const unsigned short* __restrict__ x, int* __restrict__ flag)
{
    __shared__ int cnt;
    if (threadIdx.x == 0) cnt = 0;
    __syncthreads();
    int c = 0;
    for (int i = threadIdx.x; i < 4096; i += 256) {
        const unsigned e = (x[i] >> 7) & 0xFF;
        if (e >= 0x90) c++;
    }
    atomicAdd(&cnt, c);
    __syncthreads();
    if (threadIdx.x == 0) *flag = (cnt > 64) ? 1 : 0;
}

// ---------------------------------------------------------------------------
// Kernel 0b (merged prep): small conversions -> fp32 ws (block 0), and in
// fp32 mode bf16 ws copies of x / in_proj_weight / out_w (all blocks).
// smallf: [0,3072) in_proj_bias, [3072,4096) out_b,
//         [4096,4112) exp(min(ls,MAX)), [4112,4128) head_scale.
// ---------------------------------------------------------------------------
__global__ __launch_bounds__(256) void prep_kernel(
    const int* __restrict__ flag,
    const void* __restrict__ x, const void* __restrict__ w_in, const void* __restrict__ out_w,
    const void* __restrict__ b_in, const void* __restrict__ out_b,
    const void* __restrict__ ls, const void* __restrict__ hs,
    bf16* __restrict__ xb, bf16* __restrict__ wb, bf16* __restrict__ owb,
    float* __restrict__ smallf)
{
    const int f = *flag;
    if (blockIdx.x == 0) {
        for (int idx = threadIdx.x; idx < 4128; idx += 256) {
            float v;
            if (f) {
                if (idx < 3072)      v = ((const float*)b_in)[idx];
                else if (idx < 4096) v = ((const float*)out_b)[idx - 3072];
                else if (idx < 4112) v = expf(fminf(((const float*)ls)[idx - 4096], LOGIT_MAX));
                else                 v = ((const float*)hs)[idx - 4112];
            } else {
                if (idx < 3072)      v = __bfloat162float(((const bf16*)b_in)[idx]);
                else if (idx < 4096) v = __bfloat162float(((const bf16*)out_b)[idx - 3072]);
                else if (idx < 4112) v = expf(fminf(__bfloat162float(((const bf16*)ls)[idx - 4096]), LOGIT_MAX));
                else                 v = __bfloat162float(((const bf16*)hs)[idx - 4112]);
            }
            smallf[idx] = v;
        }
    }
    if (f != 1) return;
    const size_t NX = 8388608, NW = 3145728, NO = 1048576;
    const size_t t0   = ((size_t)blockIdx.x * 256 + threadIdx.x) * 4;
    const size_t step = (size_t)gridDim.x * 256 * 4;
    for (size_t i = t0; i < NX; i += step) store4bf(xb + i, load4((const float*)x + i));
    for (size_t i = t0; i < NW; i += step) store4bf(wb + i, load4((const float*)w_in + i));
    for (size_t i = t0; i < NO; i += step) store4bf(owb + i, load4((const float*)out_w + i));
}

// ---------------------------------------------------------------------------
// Kernel 1: MFMA QKV projection, BK=64, fused q/k L2-normalize.
// C[8192x3072] = X . W^T; 128x128 tile, 4 waves 2x2.
// __launch_bounds__(256,3): request 3 waves/EU (=3 blocks/CU) — caps unified
// VGPR+AGPR at 170 (current use ~160, no spill).
// ---------------------------------------------------------------------------
__global__ __launch_bounds__(256, 3) void qkv_gemm_mfma_kernel(
    const int* __restrict__ flag,
    const bf16* __restrict__ Xws, const bf16* __restrict__ Wws,
    const bf16* __restrict__ Xdir, const bf16* __restrict__ Wdir,
    const float* __restrict__ bias_f,
    bf16* __restrict__ q, bf16* __restrict__ k, bf16* __restrict__ vt)
{
    const bf16* X = (*flag) ? Xws : Xdir;
    const bf16* W = (*flag) ? Wws : Wdir;
    __shared__ bf16 A_lds[128 * 64];
    __shared__ bf16 B_lds[128 * 64];
    const int tid  = threadIdx.x;
    const int w    = tid >> 6;
    const int lane = tid & 63;
    const int l16  = lane & 15, quad = lane >> 4;
    const int wm   = w >> 1, wn = w & 1;
    const int row0 = blockIdx.y * 128;
    const int col0 = blockIdx.x * 128;
    const int sr   = lane >> 3, sc = lane & 7;
    const int scg  = sc ^ sr;            // source chunk for swizzled staging

    f32x4 acc[4][4] = {};

    for (int kt = 0; kt < 1024; kt += 64) {
        __syncthreads();
#pragma unroll
        for (int i = 0; i < 4; i++) {
            const int br = w * 32 + i * 8;     // 8 rows per inst, br % 8 == 0
            async16(X + (size_t)(row0 + br + sr) * 1024 + kt + scg * 8, &A_lds[br * 64]);
            async16(W + (size_t)(col0 + br + sr) * 1024 + kt + scg * 8, &B_lds[br * 64]);
        }
        __syncthreads();

#pragma unroll
        for (int kh = 0; kh < 2; kh++) {
            bf16x8 af[4], bf[4];
#pragma unroll
            for (int mt = 0; mt < 4; mt++) {
                const int row = wm * 64 + mt * 16 + l16;
                af[mt] = *(const bf16x8*)&A_lds[row * 64 + (((quad + kh * 4) ^ (row & 7)) * 8)];
            }
#pragma unroll
            for (int nt = 0; nt < 4; nt++) {
                const int row = wn * 64 + nt * 16 + l16;
                bf[nt] = *(const bf16x8*)&B_lds[row * 64 + (((quad + kh * 4) ^ (row & 7)) * 8)];
            }
#pragma unroll
            for (int mt = 0; mt < 4; mt++)
#pragma unroll
                for (int nt = 0; nt < 4; nt++)
                    acc[mt][nt] = __builtin_amdgcn_mfma_f32_16x16x32_bf16(af[mt], bf[nt], acc[mt][nt], 0, 0, 0);
        }
    }

    const int cbase = col0 + wn * 64;          // wave-uniform
    const int part  = cbase >> 10;
    const int h     = (cbase & 1023) >> 6;
    float bias[4];
#pragma unroll
    for (int nt = 0; nt < 4; nt++) bias[nt] = bias_f[cbase + nt * 16 + l16];

    if (part < 2) {
        bf16* dst0 = (part == 0) ? q : k;
#pragma unroll
        for (int mt = 0; mt < 4; mt++) {
#pragma unroll
            for (int rg = 0; rg < 4; rg++) {
                const int r = row0 + wm * 64 + mt * 16 + quad * 4 + rg;
                const int l = r >> 3, nn = r & 7;
                float val[4]; float ss = 0.f;
#pragma unroll
                for (int nt = 0; nt < 4; nt++) {
                    val[nt] = acc[mt][nt][rg] + bias[nt];
                    ss += val[nt] * val[nt];
                }
                ss += __shfl_xor(ss, 1); ss += __shfl_xor(ss, 2);
                ss += __shfl_xor(ss, 4); ss += __shfl_xor(ss, 8);
                const float inv = 1.f / fmaxf(sqrtf(ss), 1e-12f);
                bf16* dp = dst0 + ((size_t)((nn * 16 + h) * 1024 + l)) * 64;
#pragma unroll
                for (int nt = 0; nt < 4; nt++)
                    dp[nt * 16 + l16] = __float2bfloat16(val[nt] * inv);
            }
        }
    } else {
#pragma unroll
        for (int mt = 0; mt < 4; mt++) {
#pragma unroll
            for (int rg = 0; rg < 4; rg++) {
                const int r = row0 + wm * 64 + mt * 16 + quad * 4 + rg;
                const int l = r >> 3, nn = r & 7;
#pragma unroll
                for (int nt = 0; nt < 4; nt++) {
                    const int d = nt * 16 + l16;
                    vt[((size_t)((nn * 16 + h) * 64 + d)) * 1024 + l] =
                        __float2bfloat16(acc[mt][nt][rg] + bias[nt]);
                }
            }
        }
    }
}

// ---------------------------------------------------------------------------
// Kernel 3: MFMA flash attention v2 + XCD swizzle.
// bid = qt*128 + nh  ->  bid % 8 == nh % 8: all 8 q-tiles of one (n,h) land
// on the same XCD; 16 nh/XCD x 256 KB K+V = 4 MB = one XCD's L2.
// ---------------------------------------------------------------------------
__global__ __launch_bounds__(256, 4) void attn_mfma_kernel(
    const bf16* __restrict__ q, const bf16* __restrict__ k,
    const bf16* __restrict__ vt, const float* __restrict__ scale_f,
    bf16* __restrict__ o)
{
    __shared__ bf16 K_lds[64][64];
    __shared__ bf16 Vt_lds[64][64];
    __shared__ bf16 P_lds[4][32][72];
    __shared__ float l_lds[4][32];

    const int bid  = blockIdx.x;
    const int qt   = bid >> 7;         // 0..7  (slow index)
    const int nh   = bid & 127;        // fast index -> XCD = nh & 7
    const int h    = nh & 15;
    const int n    = nh >> 4;
    const int tid  = threadIdx.x;
    const int w    = tid >> 6;
    const int lane = tid & 63;
    const int l16  = lane & 15;
    const int quad = lane >> 4;

    const size_t base = (size_t)nh * (1024 * 64);
    const float ls   = scale_f[4096 + h];
    const float hs   = scale_f[4112 + h];
    const float lsl2 = ls * 1.4426950408889634f;

    bf16x8 qf[2][2];
#pragma unroll
    for (int u = 0; u < 2; u++) {
        const int qrow = qt * 128 + w * 32 + u * 16 + l16;
        const bf16* qp = q + base + (size_t)qrow * 64 + quad * 8;
        qf[u][0] = *(const bf16x8*)qp;
        qf[u][1] = *(const bf16x8*)(qp + 32);
    }

    f32x4 o_acc[2][4] = {};
    float l_part[2] = {0.f, 0.f};

    const int sr = lane >> 3;
    const int sc = lane & 7;

    for (int j0 = 0; j0 < 1024; j0 += 64) {
        __syncthreads();
#pragma unroll
        for (int half = 0; half < 2; half++) {
            const int br  = w * 16 + half * 8;
            const int row = br + sr;
            const int cg  = sc ^ (row & 7);
            async16(k  + base + (size_t)(j0 + row) * 64 + cg * 8, &K_lds[br][0]);
            async16(vt + base + (size_t)row * 1024 + j0 + cg * 8, &Vt_lds[br][0]);
        }
        __syncthreads();

        f32x4 s8[2][4];
#pragma unroll
        for (int s = 0; s < 4; s++) {
            const int krow = s * 16 + l16;
            const int swz  = krow & 7;
            const bf16x8 kf0 = *(const bf16x8*)&K_lds[krow][(quad ^ swz) * 8];
            const bf16x8 kf1 = *(const bf16x8*)&K_lds[krow][((quad + 4) ^ swz) * 8];
#pragma unroll
            for (int u = 0; u < 2; u++) {
                f32x4 a = {};
                a = __builtin_amdgcn_mfma_f32_16x16x32_bf16(kf0, qf[u][0], a, 0, 0, 0);
                a = __builtin_amdgcn_mfma_f32_16x16x32_bf16(kf1, qf[u][1], a, 0, 0, 0);
                s8[u][s] = a;
            }
        }

#pragma unroll
        for (int u = 0; u < 2; u++) {
#pragma unroll
            for (int s = 0; s < 4; s++) {
                union { bf16 b[4]; uint2 uu; } pk;
                float sum = 0.f;
#pragma unroll
                for (int r = 0; r < 4; r++) {
                    const float p = exp2f(fmaf(s8[u][s][r], lsl2, -lsl2));
                    pk.b[r] = __float2bfloat16(p);
                    sum += p;
                }
                l_part[u] += sum;
                *(uint2*)&P_lds[w][u * 16 + l16][s * 16 + quad * 4] = pk.uu;
            }
        }

        bf16x8 pf[2][2];
#pragma unroll
        for (int u = 0; u < 2; u++) {
            pf[u][0] = *(const bf16x8*)&P_lds[w][u * 16 + l16][quad * 8];
            pf[u][1] = *(const bf16x8*)&P_lds[w][u * 16 + l16][32 + quad * 8];
        }
#pragma unroll
        for (int ds = 0; ds < 4; ds++) {
            const int vrow = ds * 16 + l16;
            const int swz  = vrow & 7;
            const bf16x8 vf0 = *(const bf16x8*)&Vt_lds[vrow][(quad ^ swz) * 8];
            const bf16x8 vf1 = *(const bf16x8*)&Vt_lds[vrow][((quad + 4) ^ swz) * 8];
#pragma unroll
            for (int u = 0; u < 2; u++) {
                o_acc[u][ds] = __builtin_amdgcn_mfma_f32_16x16x32_bf16(pf[u][0], vf0, o_acc[u][ds], 0, 0, 0);
                o_acc[u][ds] = __builtin_amdgcn_mfma_f32_16x16x32_bf16(pf[u][1], vf1, o_acc[u][ds], 0, 0, 0);
            }
        }
    }

#pragma unroll
    for (int u = 0; u < 2; u++) {
        float v = l_part[u];
        v += __shfl_xor(v, 16);
        v += __shfl_xor(v, 32);
        l_lds[w][u * 16 + l16] = v;
    }

#pragma unroll
    for (int u = 0; u < 2; u++) {
#pragma unroll
        for (int r = 0; r < 4; r++) {
            const float inv = hs / l_lds[w][u * 16 + quad * 4 + r];
            const int row_l = qt * 128 + w * 32 + u * 16 + quad * 4 + r;
            bf16* dst = o + ((size_t)row_l * 8 + n) * 1024 + h * 64 + l16;
#pragma unroll
            for (int ds = 0; ds < 4; ds++)
                dst[ds * 16] = __float2bfloat16(o_acc[u][ds][r] * inv);
        }
    }
}

// ---------------------------------------------------------------------------
// Kernel 4: MFMA out projection, BK=64, single launch (runtime output dtype).
// out[8192x1024] = A . W^T + b.
// ---------------------------------------------------------------------------
__global__ __launch_bounds__(256, 3) void out_gemm_mfma_kernel(
    const int* __restrict__ flag,
    const bf16* __restrict__ A,
    const bf16* __restrict__ Bws, const bf16* __restrict__ Bdir,
    const float* __restrict__ bias_f,
    float* __restrict__ outf, bf16* __restrict__ outb)
{
    const int f = *flag;
    const bf16* B = f ? Bws : Bdir;
    __shared__ bf16 A_lds[128 * 64];
    __shared__ bf16 B_lds[128 * 64];
    const int tid  = threadIdx.x;
    const int w    = tid >> 6;
    const int lane = tid & 63;
    const int l16  = lane & 15, quad = lane >> 4;
    const int wm   = w >> 1, wn = w & 1;
    const int row0 = blockIdx.y * 128;
    const int col0 = blockIdx.x * 128;
    const int sr   = lane >> 3, sc = lane & 7;
    const int scg  = sc ^ sr;

    f32x4 acc[4][4] = {};

    for (int kt = 0; kt < 1024; kt += 64) {
        __syncthreads();
#pragma unroll
        for (int i = 0; i < 4; i++) {
            const int br = w * 32 + i * 8;
            async16(A + (size_t)(row0 + br + sr) * 1024 + kt + scg * 8, &A_lds[br * 64]);
            async16(B + (size_t)(col0 + br + sr) * 1024 + kt + scg * 8, &B_lds[br * 64]);
        }
        __syncthreads();

#pragma unroll
        for (int kh = 0; kh < 2; kh++) {
            bf16x8 af[4], bf[4];
#pragma unroll
            for (int mt = 0; mt < 4; mt++) {
                const int row = wm * 64 + mt * 16 + l16;
                af[mt] = *(const bf16x8*)&A_lds[row * 64 + (((quad + kh * 4) ^ (row & 7)) * 8)];
            }
#pragma unroll
            for (int nt = 0; nt < 4; nt++) {
                const int row = wn * 64 + nt * 16 + l16;
                bf[nt] = *(const bf16x8*)&B_lds[row * 64 + (((quad + kh * 4) ^ (row & 7)) * 8)];
            }
#pragma unroll
            for (int mt = 0; mt < 4; mt++)
#pragma unroll
                for (int nt = 0; nt < 4; nt++)
                    acc[mt][nt] = __builtin_amdgcn_mfma_f32_16x16x32_bf16(af[mt], bf[nt], acc[mt][nt], 0, 0, 0);
        }
    }

#pragma unroll
    for (int mt = 0; mt < 4; mt++) {
        const int rbase = row0 + wm * 64 + mt * 16 + quad * 4;
#pragma unroll
        for (int nt = 0; nt < 4; nt++) {
            const int c = col0 + wn * 64 + nt * 16 + l16;
            const float bias = bias_f[c];
#pragma unroll
            for (int rg = 0; rg < 4; rg++) {
                const float v = acc[mt][nt][rg] + bias;
                const size_t idx = (size_t)(rbase + rg) * 1024 + c;
                if (f) outf[idx] = v; else outb[idx] = __float2bfloat16(v);
            }
        }
    }
}

// ---------------------------------------------------------------------------
extern "C" void kernel_launch(void* const* d_in, const int* in_sizes, int n_in,
                              void* d_out, int out_size, void* d_ws, size_t ws_size,
                              hipStream_t stream)
{
    const size_t SEG = (size_t)8 * 16 * 1024 * 64;   // 8388608 elems
    bf16* qn  = (bf16*)d_ws;
    bf16* kn  = qn + SEG;
    bf16* vt  = kn + SEG;
    bf16* ow  = vt + SEG;
    bf16* xb  = ow + SEG;                  // bf16 copy of x (fp32 mode)
    bf16* wb  = xb + SEG;                  // bf16 copy of in_proj_weight
    bf16* owb = wb + 3145728;              // bf16 copy of out_w
    float* smallf = (float*)(owb + 1048576);   // 4128 floats
    int*   flag   = (int*)(smallf + 4128);

    detect_kernel<<<1, 256, 0, stream>>>((const unsigned short*)d_in[0], flag);

    prep_kernel<<<4096, 256, 0, stream>>>(flag,
        d_in[0], d_in[1], d_in[5], d_in[2], d_in[6], d_in[3], d_in[4],
        xb, wb, owb, smallf);

    // 1) qkv projection (MFMA, BK=64) + fused q/k L2-normalize
    qkv_gemm_mfma_kernel<<<dim3(3072 / 128, 8192 / 128), 256, 0, stream>>>(
        flag, xb, wb, (const bf16*)d_in[0], (const bf16*)d_in[1], smallf, qn, kn, vt);

    // 2) flash attention v2 (MFMA, fixed-max softmax, XCD-local nh)
    attn_mfma_kernel<<<dim3(128 * 8), 256, 0, stream>>>(qn, kn, vt, smallf, ow);

    // 3) out projection (MFMA, BK=64), single launch
    out_gemm_mfma_kernel<<<dim3(1024 / 128, 8192 / 128), 256, 0, stream>>>(
        flag, ow, owb, (const bf16*)d_in[5], smallf + 3072,
        (float*)d_out, (bf16*)d_out);
}